// Round 5
// baseline (890.365 us; speedup 1.0000x reference)
//
#include <hip/hip_runtime.h>
#include <hip/hip_bf16.h>

#define NEG_SLOPE 0.2f
using bf16 = __hip_bfloat16;

typedef __attribute__((ext_vector_type(8))) short short8;   // 8 bf16 (4 VGPRs)
typedef __attribute__((ext_vector_type(4))) float f32x4;
#define MFMA16(a, b, c) __builtin_amdgcn_mfma_f32_16x16x32_bf16(a, b, c, 0, 0, 0)

__device__ __forceinline__ float bflo(unsigned u) { return __uint_as_float(u << 16); }
__device__ __forceinline__ float bfhi(unsigned u) { return __uint_as_float(u & 0xffff0000u); }

__device__ __forceinline__ float edge_w(float q, float adh) {
  float t = q + adh;
  t = (t > 0.f) ? t : NEG_SLOPE * t;
  return __expf(t);
}

__device__ __forceinline__ void accum_row(const uint4 r, float v, float (&acc)[8]) {
  acc[0] = fmaf(v, bflo(r.x), acc[0]);
  acc[1] = fmaf(v, bfhi(r.x), acc[1]);
  acc[2] = fmaf(v, bflo(r.y), acc[2]);
  acc[3] = fmaf(v, bfhi(r.y), acc[3]);
  acc[4] = fmaf(v, bflo(r.z), acc[4]);
  acc[5] = fmaf(v, bfhi(r.z), acc[5]);
  acc[6] = fmaf(v, bflo(r.w), acc[6]);
  acc[7] = fmaf(v, bfhi(r.w), acc[7]);
}

// MFMA-fragment packed offset: (tile, kc, lk, r, e) for 16-row tiles, K=128
__device__ __forceinline__ size_t frag_off(int row, int k) {
  return (size_t)(row >> 4) * 2048 + (k >> 5) * 512 + ((k >> 3) & 3) * 128 +
         (row & 15) * 8 + (k & 7);
}

// ---------------- ONE fused setup kernel: cast_x->xbX, cast_wt->WtX, w1p, w2p, b3p, deg
__global__ __launch_bounds__(256)
void setup_kernel(const float* __restrict__ x, const int* __restrict__ ei,
                  const float* __restrict__ g1_W,
                  const float* __restrict__ sk1_W, const float* __restrict__ sk1_b,
                  const float* __restrict__ sk2_W, const float* __restrict__ sk2_b,
                  const float* __restrict__ g3_W,
                  bf16* __restrict__ xbX, bf16* __restrict__ WtX,
                  float* __restrict__ W1pT, float* __restrict__ W2pT,
                  float* __restrict__ b3p, int* __restrict__ deg,
                  int N, int Np, int E, int EP,
                  int bX, int bWT, int bW1, int bW2, int bB3) {
  const int b = blockIdx.x;
  const int t = threadIdx.x;
  if (b < bX) {                       // x -> xbX (packed MFMA A-frag layout, zero pad)
    const int total4 = Np * 32;
    const int stride = bX * 256;
    for (int i = b * 256 + t; i < total4; i += stride) {
      int row = i >> 5, kq = (i & 31) * 4;
      float4 v = make_float4(0.f, 0.f, 0.f, 0.f);
      if (row < N) v = reinterpret_cast<const float4*>(x)[i];
      union { bf16 bv[4]; ushort4 u; } pk;
      pk.bv[0] = __float2bfloat16(v.x); pk.bv[1] = __float2bfloat16(v.y);
      pk.bv[2] = __float2bfloat16(v.z); pk.bv[3] = __float2bfloat16(v.w);
      *reinterpret_cast<ushort4*>(&xbX[frag_off(row, kq)]) = pk.u;
    }
  } else if (b < bWT) {               // g1_W -> WtX (packed MFMA B-frag layout)
    int i = (b - bX) * 256 + t;       // 65536 exactly
    int k = i >> 9, c = i & 511;
    WtX[frag_off(c, k)] = __float2bfloat16(g1_W[k * 512 + c]);
  } else if (b < bW1) {               // W1pT[16][128]
    int i = (b - bWT) * 256 + t;      // 2048
    int j = i >> 7, k = i & 127;
    float acc = 0.f;
    for (int m = 0; m < 512; m++) acc += sk1_W[k * 512 + m] * g3_W[m * 16 + j];
    W1pT[i] = acc;
  } else if (b < bW2) {               // W2pT[16][512]
    int i = (b - bW1) * 256 + t;      // 8192
    int j = i >> 9, c = i & 511;
    float acc = 0.f;
    for (int m = 0; m < 512; m++) acc += sk2_W[c * 512 + m] * g3_W[(512 + m) * 16 + j];
    W2pT[i] = acc;
  } else if (b < bB3) {               // b3p[16]
    if (t < 16) {
      float acc = 0.f;
      for (int m = 0; m < 512; m++)
        acc += sk1_b[m] * g3_W[m * 16 + t] + sk2_b[m] * g3_W[(512 + m) * 16 + t];
      b3p[t] = acc;
    }
  } else {                            // degree histogram
    int e = (b - bB3) * 256 + t;
    if (e < EP) {
      int d = (e < E) ? ei[E + e] : (e - E);
      atomicAdd(&deg[d], 1);
    }
  }
}

// ---------------- MFMA GEMM: h1 = x @ g1_W (packed frags, fully coalesced loads)
// Block 256 thr = 4 waves (2M x 2N). Block tile 64M x 128N. Wave tile 32M x 64N = 1 head.
__global__ __launch_bounds__(256)
void gemm_h1_kernel(const bf16* __restrict__ xbX, const bf16* __restrict__ WtX,
                    const float* __restrict__ att_s, const float* __restrict__ att_d,
                    bf16* __restrict__ H1, float* __restrict__ a_src, float* __restrict__ a_dst,
                    int M) {
  const int t = threadIdx.x;
  const int w = t >> 6, l = t & 63;
  const int wm = w & 1, wn = w >> 1;
  const int m0 = blockIdx.x * 64 + wm * 32;
  const int n0 = blockIdx.y * 128 + wn * 64;
  const int head = n0 >> 6;
  const int lr = l & 15, lk = l >> 4;
  const bf16* aBase = xbX + (size_t)(m0 >> 4) * 2048 + l * 8;
  const bf16* bBase = WtX + (size_t)(n0 >> 4) * 2048 + l * 8;
  f32x4 acc[2][4] = {};
  #pragma unroll
  for (int kc = 0; kc < 4; kc++) {
    short8 av0 = *reinterpret_cast<const short8*>(aBase + kc * 512);
    short8 av1 = *reinterpret_cast<const short8*>(aBase + 2048 + kc * 512);
    short8 bv0 = *reinterpret_cast<const short8*>(bBase + 0 * 2048 + kc * 512);
    short8 bv1 = *reinterpret_cast<const short8*>(bBase + 1 * 2048 + kc * 512);
    short8 bv2 = *reinterpret_cast<const short8*>(bBase + 2 * 2048 + kc * 512);
    short8 bv3 = *reinterpret_cast<const short8*>(bBase + 3 * 2048 + kc * 512);
    acc[0][0] = MFMA16(av0, bv0, acc[0][0]);
    acc[0][1] = MFMA16(av0, bv1, acc[0][1]);
    acc[0][2] = MFMA16(av0, bv2, acc[0][2]);
    acc[0][3] = MFMA16(av0, bv3, acc[0][3]);
    acc[1][0] = MFMA16(av1, bv0, acc[1][0]);
    acc[1][1] = MFMA16(av1, bv1, acc[1][1]);
    acc[1][2] = MFMA16(av1, bv2, acc[1][2]);
    acc[1][3] = MFMA16(av1, bv3, acc[1][3]);
  }
  float as_r[4], ad_r[4];
  #pragma unroll
  for (int ni = 0; ni < 4; ni++) {
    as_r[ni] = att_s[head * 64 + ni * 16 + lr];
    ad_r[ni] = att_d[head * 64 + ni * 16 + lr];
  }
  #pragma unroll
  for (int mi = 0; mi < 2; mi++) {
    #pragma unroll
    for (int r = 0; r < 4; r++) {
      int row = m0 + mi * 16 + lk * 4 + r;
      bool ok = row < M;
      float vs = 0.f, vd = 0.f;
      #pragma unroll
      for (int ni = 0; ni < 4; ni++) {
        float v = acc[mi][ni][r];
        vs += v * as_r[ni]; vd += v * ad_r[ni];
        if (ok) H1[(size_t)row * 512 + n0 + ni * 16 + lr] = __float2bfloat16(v);
      }
      vs += __shfl_xor(vs, 1); vs += __shfl_xor(vs, 2);
      vs += __shfl_xor(vs, 4); vs += __shfl_xor(vs, 8);
      vd += __shfl_xor(vd, 1); vd += __shfl_xor(vd, 2);
      vd += __shfl_xor(vd, 4); vd += __shfl_xor(vd, 8);
      if (ok && lr == 0) {
        a_src[(size_t)row * 8 + head] = vs;
        a_dst[(size_t)row * 8 + head] = vd;
      }
    }
  }
}

// ---------------- CSR build
__global__ __launch_bounds__(1024)
void scan_kernel(const int* __restrict__ deg, int* __restrict__ offs, int n) {
  __shared__ int sums[1024];
  int t = threadIdx.x;
  int chunk = (n + 1023) >> 10;
  int lo = t * chunk, hi = min(lo + chunk, n);
  int s = 0;
  for (int i = lo; i < hi; i++) s += deg[i];
  sums[t] = s;
  __syncthreads();
  for (int step = 1; step < 1024; step <<= 1) {
    int v = (t >= step) ? sums[t - step] : 0;
    __syncthreads();
    sums[t] += v;
    __syncthreads();
  }
  int run = (t == 0) ? 0 : sums[t - 1];
  for (int i = lo; i < hi; i++) { offs[i] = run; run += deg[i]; }
  if (t == 1023) offs[n] = sums[1023];
}

__global__ void scatter_kernel(const int* __restrict__ ei, const int* __restrict__ offs,
                               int* __restrict__ cursor, int* __restrict__ esrc, int E, int EP) {
  int e = blockIdx.x * blockDim.x + threadIdx.x;
  if (e >= EP) return;
  int s = (e < E) ? ei[e] : (e - E);
  int d = (e < E) ? ei[E + e] : (e - E);
  int pos = offs[d] + atomicAdd(&cursor[d], 1);
  esrc[pos] = s;
}

// ---------------- FUSED: gat1 softmax-aggregation + skip-folded h3 GEMV + att3 dots.
// One wave per node; lane l owns channels [8l, 8l+8). LDS-transpose GEMV tail.
__global__ __launch_bounds__(256)
void agg1_h3_kernel(const int* __restrict__ offs, const int* __restrict__ esrc,
                    const float* __restrict__ a_src1, const float* __restrict__ a_dst1,
                    const bf16* __restrict__ H1, const float* __restrict__ g1_b,
                    const float* __restrict__ X,
                    const float* __restrict__ W1pT, const float* __restrict__ W2pT,
                    const float* __restrict__ b3p,
                    const float* __restrict__ g3_as, const float* __restrict__ g3_ad,
                    float* __restrict__ H3, float* __restrict__ a3s, float* __restrict__ a3d,
                    int N) {
  __shared__ float x1s[4][512];
  const int wv = threadIdx.x >> 6;
  const int l = threadIdx.x & 63;
  int n = blockIdx.x * 4 + wv;
  if (n >= N) n = N - 1;                 // clamp (duplicate work; keeps barrier safe)
  const int h = l >> 3;
  const float adh = a_dst1[n * 8 + h];
  const uint4* __restrict__ H1v = reinterpret_cast<const uint4*>(H1);
  const int lo = offs[n], hi = offs[n + 1];
  float acc[8] = {0.f, 0.f, 0.f, 0.f, 0.f, 0.f, 0.f, 0.f};
  float psum = 0.f;
  int i = lo;
  for (; i + 8 <= hi; i += 8) {          // 8 rows in flight
    int s0 = esrc[i+0], s1 = esrc[i+1], s2 = esrc[i+2], s3 = esrc[i+3];
    int s4 = esrc[i+4], s5 = esrc[i+5], s6 = esrc[i+6], s7 = esrc[i+7];
    float q0 = a_src1[s0*8+h], q1 = a_src1[s1*8+h], q2 = a_src1[s2*8+h], q3 = a_src1[s3*8+h];
    float q4 = a_src1[s4*8+h], q5 = a_src1[s5*8+h], q6 = a_src1[s6*8+h], q7 = a_src1[s7*8+h];
    uint4 r0 = H1v[(size_t)s0*64+l], r1 = H1v[(size_t)s1*64+l];
    uint4 r2 = H1v[(size_t)s2*64+l], r3 = H1v[(size_t)s3*64+l];
    uint4 r4 = H1v[(size_t)s4*64+l], r5 = H1v[(size_t)s5*64+l];
    uint4 r6 = H1v[(size_t)s6*64+l], r7 = H1v[(size_t)s7*64+l];
    float v0 = edge_w(q0, adh), v1 = edge_w(q1, adh), v2 = edge_w(q2, adh), v3 = edge_w(q3, adh);
    float v4 = edge_w(q4, adh), v5 = edge_w(q5, adh), v6 = edge_w(q6, adh), v7 = edge_w(q7, adh);
    psum += (v0 + v1 + v2 + v3) + (v4 + v5 + v6 + v7);
    accum_row(r0, v0, acc); accum_row(r1, v1, acc);
    accum_row(r2, v2, acc); accum_row(r3, v3, acc);
    accum_row(r4, v4, acc); accum_row(r5, v5, acc);
    accum_row(r6, v6, acc); accum_row(r7, v7, acc);
  }
  if (i + 4 <= hi) {
    int s0 = esrc[i+0], s1 = esrc[i+1], s2 = esrc[i+2], s3 = esrc[i+3];
    float q0 = a_src1[s0*8+h], q1 = a_src1[s1*8+h], q2 = a_src1[s2*8+h], q3 = a_src1[s3*8+h];
    uint4 r0 = H1v[(size_t)s0*64+l], r1 = H1v[(size_t)s1*64+l];
    uint4 r2 = H1v[(size_t)s2*64+l], r3 = H1v[(size_t)s3*64+l];
    float v0 = edge_w(q0, adh), v1 = edge_w(q1, adh), v2 = edge_w(q2, adh), v3 = edge_w(q3, adh);
    psum += v0 + v1 + v2 + v3;
    accum_row(r0, v0, acc); accum_row(r1, v1, acc);
    accum_row(r2, v2, acc); accum_row(r3, v3, acc);
    i += 4;
  }
  for (; i < hi; i++) {
    int s = esrc[i];
    float q = a_src1[(size_t)s*8+h];
    uint4 r = H1v[(size_t)s*64+l];
    float v = edge_w(q, adh);
    psum += v;
    accum_row(r, v, acc);
  }
  const float inv = 1.f / (psum + 1e-16f);
  float4 ba = *reinterpret_cast<const float4*>(&g1_b[l * 8]);
  float4 bb = *reinterpret_cast<const float4*>(&g1_b[l * 8 + 4]);
  *reinterpret_cast<float4*>(&x1s[wv][l * 8]) =
      make_float4(acc[0]*inv + ba.x, acc[1]*inv + ba.y, acc[2]*inv + ba.z, acc[3]*inv + ba.w);
  *reinterpret_cast<float4*>(&x1s[wv][l * 8 + 4]) =
      make_float4(acc[4]*inv + bb.x, acc[5]*inv + bb.y, acc[6]*inv + bb.z, acc[7]*inv + bb.w);
  __syncthreads();
  // ---- GEMV: lane (j = l&15, seg = l>>4); 4 segs x 128 x1-ch (+32 x-ch); 2 shuffles
  const int j = l & 15, seg = l >> 4;
  float p = 0.f;
  {
    const float* x1r = &x1s[wv][seg * 128];
    const float* w2r = &W2pT[j * 512 + seg * 128];
    #pragma unroll
    for (int c = 0; c < 128; c += 4) {
      float4 a = *reinterpret_cast<const float4*>(x1r + c);
      float4 b = *reinterpret_cast<const float4*>(w2r + c);
      p += a.x * b.x + a.y * b.y + a.z * b.z + a.w * b.w;
    }
  }
  {
    const float* xr = &X[(size_t)n * 128 + seg * 32];
    const float* w1r = &W1pT[j * 128 + seg * 32];
    #pragma unroll
    for (int c = 0; c < 32; c += 4) {
      float4 a = *reinterpret_cast<const float4*>(xr + c);
      float4 b = *reinterpret_cast<const float4*>(w1r + c);
      p += a.x * b.x + a.y * b.y + a.z * b.z + a.w * b.w;
    }
  }
  p += __shfl_xor(p, 16);
  p += __shfl_xor(p, 32);
  float o = p + b3p[j];
  if (l < 16) H3[(size_t)n * 16 + j] = o;
  float vs = (l < 16) ? o * g3_as[j] : 0.f;
  float vd = (l < 16) ? o * g3_ad[j] : 0.f;
  vs += __shfl_xor(vs, 1); vs += __shfl_xor(vs, 2);
  vs += __shfl_xor(vs, 4); vs += __shfl_xor(vs, 8);
  vd += __shfl_xor(vd, 1); vd += __shfl_xor(vd, 2);
  vd += __shfl_xor(vd, 4); vd += __shfl_xor(vd, 8);
  if (l == 0) { a3s[n] = vs; a3d[n] = vd; }
}

// ---------------- gat3 aggregation -> d_out. Wave/node, 4 groups x 16 ch, unroll 4.
__global__ __launch_bounds__(256)
void agg3_kernel(const int* __restrict__ offs, const int* __restrict__ esrc,
                 const float* __restrict__ a3s, const float* __restrict__ a3d,
                 const float* __restrict__ H3, const float* __restrict__ g3_b,
                 float* __restrict__ out, int N) {
  const int l = threadIdx.x & 63;
  const int n = blockIdx.x * 4 + (threadIdx.x >> 6);
  if (n >= N) return;
  const int g = l >> 4, j = l & 15;
  const float ad = a3d[n];
  const int lo = offs[n], hi = offs[n + 1];
  float acc = 0.f, psum = 0.f;
  int i = lo + g;
  for (; i + 12 < hi; i += 16) {         // 4 edges in flight per lane-group
    int s0 = esrc[i], s1 = esrc[i + 4], s2 = esrc[i + 8], s3 = esrc[i + 12];
    float q0 = a3s[s0], q1 = a3s[s1], q2 = a3s[s2], q3 = a3s[s3];
    float h0 = H3[(size_t)s0 * 16 + j], h1 = H3[(size_t)s1 * 16 + j];
    float h2 = H3[(size_t)s2 * 16 + j], h3v = H3[(size_t)s3 * 16 + j];
    float v0 = edge_w(q0, ad), v1 = edge_w(q1, ad);
    float v2 = edge_w(q2, ad), v3 = edge_w(q3, ad);
    psum += (v0 + v1) + (v2 + v3);
    acc = fmaf(v0, h0, acc); acc = fmaf(v1, h1, acc);
    acc = fmaf(v2, h2, acc); acc = fmaf(v3, h3v, acc);
  }
  for (; i < hi; i += 4) {
    int s = esrc[i];
    float v = edge_w(a3s[s], ad);
    psum += v;
    acc = fmaf(v, H3[(size_t)s * 16 + j], acc);
  }
  acc += __shfl_xor(acc, 16);  acc += __shfl_xor(acc, 32);
  psum += __shfl_xor(psum, 16); psum += __shfl_xor(psum, 32);
  if (l < 16) out[(size_t)n * 16 + j] = acc / (psum + 1e-16f) + g3_b[j];
}

__global__ void sentinel_kernel(float* out) { out[threadIdx.x] = -1e9f; }

extern "C" void kernel_launch(void* const* d_in, const int* in_sizes, int n_in,
                              void* d_out, int out_size, void* d_ws, size_t ws_size,
                              hipStream_t stream) {
  const float* x      = (const float*)d_in[0];
  const int*   ei     = (const int*)d_in[1];
  const float* g1_W   = (const float*)d_in[2];
  const float* g1_as  = (const float*)d_in[3];
  const float* g1_ad  = (const float*)d_in[4];
  const float* g1_b   = (const float*)d_in[5];
  const float* sk1_W  = (const float*)d_in[6];
  const float* sk1_b  = (const float*)d_in[7];
  const float* sk2_W  = (const float*)d_in[8];
  const float* sk2_b  = (const float*)d_in[9];
  const float* g3_W   = (const float*)d_in[10];
  const float* g3_as  = (const float*)d_in[11];
  const float* g3_ad  = (const float*)d_in[12];
  const float* g3_b   = (const float*)d_in[13];
  float* out = (float*)d_out;

  const int N  = in_sizes[0] / 128;
  const int E  = in_sizes[1] / 2;
  const int EP = E + N;
  const int Mt = (N + 63) / 64;
  const int Np = Mt * 64;

  char* w = (char*)d_ws;
  size_t off = 0;
  auto alloc = [&](size_t bytes) -> void* {
    void* p = w + off;
    off = (off + bytes + 255) & ~(size_t)255;
    return p;
  };

  // zero-init block (single memset)
  int* deg    = (int*)alloc((size_t)N * 4);
  int* cursor = (int*)alloc((size_t)N * 4);
  size_t zbytes = off;
  // rest of workspace
  int*   offs   = (int*)alloc((size_t)(N + 1) * 4);
  int*   esrc   = (int*)alloc((size_t)EP * 4);
  bf16*  xbX    = (bf16*)alloc((size_t)Np * 128 * 2);
  bf16*  WtX    = (bf16*)alloc(512 * 128 * 2);
  bf16*  h1     = (bf16*)alloc((size_t)N * 512 * 2);
  float* a_src1 = (float*)alloc((size_t)N * 8 * 4);
  float* a_dst1 = (float*)alloc((size_t)N * 8 * 4);
  float* h3     = (float*)alloc((size_t)N * 16 * 4);
  float* a_src3 = (float*)alloc((size_t)N * 4);
  float* a_dst3 = (float*)alloc((size_t)N * 4);
  float* W1pT   = (float*)alloc(128 * 16 * 4);
  float* W2pT   = (float*)alloc(512 * 16 * 4);
  float* b3p    = (float*)alloc(16 * 4);
  (void)n_in; (void)out_size;

  if (off > ws_size) {  // workspace too small: fail loudly but safely
    sentinel_kernel<<<1, 16, 0, stream>>>(out);
    return;
  }

  hipMemsetAsync(d_ws, 0, zbytes, stream);

  const int eb = (EP + 255) / 256;
  const int nb4 = (N + 3) / 4;
  // setup partition: [0,bX) cast_x | [bX,bWT) cast_wt | w1p | w2p | b3p | deg
  const int bX = 1024, bWT = bX + 256, bW1 = bWT + 8, bW2 = bW1 + 32, bB3 = bW2 + 1;

  setup_kernel<<<bB3 + eb, 256, 0, stream>>>(
      x, ei, g1_W, sk1_W, sk1_b, sk2_W, sk2_b, g3_W,
      xbX, WtX, W1pT, W2pT, b3p, deg, N, Np, E, EP, bX, bWT, bW1, bW2, bB3);

  gemm_h1_kernel<<<dim3(Mt, 4), 256, 0, stream>>>(
      xbX, WtX, g1_as, g1_ad, h1, a_src1, a_dst1, N);

  scan_kernel<<<1, 1024, 0, stream>>>(deg, offs, N);
  scatter_kernel<<<eb, 256, 0, stream>>>(ei, offs, cursor, esrc, E, EP);

  agg1_h3_kernel<<<nb4, 256, 0, stream>>>(offs, esrc, a_src1, a_dst1, h1, g1_b, x,
                                          W1pT, W2pT, b3p, g3_as, g3_ad,
                                          h3, a_src3, a_dst3, N);

  agg3_kernel<<<nb4, 256, 0, stream>>>(offs, esrc, a_src3, a_dst3, h3, g3_b, out, N);
}

// Round 6
// 581.821 us; speedup vs baseline: 1.5303x; 1.5303x over previous
//
#include <hip/hip_runtime.h>
#include <hip/hip_bf16.h>

#define NEG_SLOPE 0.2f
using bf16 = __hip_bfloat16;

typedef __attribute__((ext_vector_type(8))) short short8;   // 8 bf16 (4 VGPRs)
typedef __attribute__((ext_vector_type(4))) float f32x4;
#define MFMA16(a, b, c) __builtin_amdgcn_mfma_f32_16x16x32_bf16(a, b, c, 0, 0, 0)

__device__ __forceinline__ float bflo(unsigned u) { return __uint_as_float(u << 16); }
__device__ __forceinline__ float bfhi(unsigned u) { return __uint_as_float(u & 0xffff0000u); }

__device__ __forceinline__ float edge_w(float q, float adh) {
  float t = q + adh;
  t = (t > 0.f) ? t : NEG_SLOPE * t;
  return __expf(t);
}

__device__ __forceinline__ void accum_row(const uint4 r, float v, float (&acc)[8]) {
  acc[0] = fmaf(v, bflo(r.x), acc[0]);
  acc[1] = fmaf(v, bfhi(r.x), acc[1]);
  acc[2] = fmaf(v, bflo(r.y), acc[2]);
  acc[3] = fmaf(v, bfhi(r.y), acc[3]);
  acc[4] = fmaf(v, bflo(r.z), acc[4]);
  acc[5] = fmaf(v, bfhi(r.z), acc[5]);
  acc[6] = fmaf(v, bflo(r.w), acc[6]);
  acc[7] = fmaf(v, bfhi(r.w), acc[7]);
}

// MFMA-fragment packed offset: (tile, kc, lk, r, e) for 16-row tiles, K=128
__device__ __forceinline__ size_t frag_off(int row, int k) {
  return (size_t)(row >> 4) * 2048 + (k >> 5) * 512 + ((k >> 3) & 3) * 128 +
         (row & 15) * 8 + (k & 7);
}

// ---------------- ONE fused setup kernel: cast_x->xbX, cast_wt->WtX, w1p, w2p, b3p, deg
__global__ __launch_bounds__(256)
void setup_kernel(const float* __restrict__ x, const int* __restrict__ ei,
                  const float* __restrict__ g1_W,
                  const float* __restrict__ sk1_W, const float* __restrict__ sk1_b,
                  const float* __restrict__ sk2_W, const float* __restrict__ sk2_b,
                  const float* __restrict__ g3_W,
                  bf16* __restrict__ xbX, bf16* __restrict__ WtX,
                  float* __restrict__ W1pT, float* __restrict__ W2pT,
                  float* __restrict__ b3p, int* __restrict__ deg,
                  int N, int Np, int E, int EP,
                  int bX, int bWT, int bW1, int bW2, int bB3) {
  const int b = blockIdx.x;
  const int t = threadIdx.x;
  if (b < bX) {                       // x -> xbX (packed MFMA A-frag layout, zero pad)
    const int total4 = Np * 32;
    const int stride = bX * 256;
    for (int i = b * 256 + t; i < total4; i += stride) {
      int row = i >> 5, kq = (i & 31) * 4;
      float4 v = make_float4(0.f, 0.f, 0.f, 0.f);
      if (row < N) v = reinterpret_cast<const float4*>(x)[i];
      union { bf16 bv[4]; ushort4 u; } pk;
      pk.bv[0] = __float2bfloat16(v.x); pk.bv[1] = __float2bfloat16(v.y);
      pk.bv[2] = __float2bfloat16(v.z); pk.bv[3] = __float2bfloat16(v.w);
      *reinterpret_cast<ushort4*>(&xbX[frag_off(row, kq)]) = pk.u;
    }
  } else if (b < bWT) {               // g1_W -> WtX (packed MFMA B-frag layout)
    int i = (b - bX) * 256 + t;       // 65536 exactly
    int k = i >> 9, c = i & 511;
    WtX[frag_off(c, k)] = __float2bfloat16(g1_W[k * 512 + c]);
  } else if (b < bW1) {               // W1pT[16][128]
    int i = (b - bWT) * 256 + t;      // 2048
    int j = i >> 7, k = i & 127;
    float acc = 0.f;
    for (int m = 0; m < 512; m++) acc += sk1_W[k * 512 + m] * g3_W[m * 16 + j];
    W1pT[i] = acc;
  } else if (b < bW2) {               // W2pT[16][512]
    int i = (b - bW1) * 256 + t;      // 8192
    int j = i >> 9, c = i & 511;
    float acc = 0.f;
    for (int m = 0; m < 512; m++) acc += sk2_W[c * 512 + m] * g3_W[(512 + m) * 16 + j];
    W2pT[i] = acc;
  } else if (b < bB3) {               // b3p[16]
    if (t < 16) {
      float acc = 0.f;
      for (int m = 0; m < 512; m++)
        acc += sk1_b[m] * g3_W[m * 16 + t] + sk2_b[m] * g3_W[(512 + m) * 16 + t];
      b3p[t] = acc;
    }
  } else {                            // degree histogram
    int e = (b - bB3) * 256 + t;
    if (e < EP) {
      int d = (e < E) ? ei[E + e] : (e - E);
      atomicAdd(&deg[d], 1);
    }
  }
}

// ---------------- MFMA GEMM: h1 = x @ g1_W (packed frags, fully coalesced loads)
// Block 256 thr = 4 waves (2M x 2N). Block tile 64M x 128N. Wave tile 32M x 64N = 1 head.
__global__ __launch_bounds__(256)
void gemm_h1_kernel(const bf16* __restrict__ xbX, const bf16* __restrict__ WtX,
                    const float* __restrict__ att_s, const float* __restrict__ att_d,
                    bf16* __restrict__ H1, float* __restrict__ a_src, float* __restrict__ a_dst,
                    int M) {
  const int t = threadIdx.x;
  const int w = t >> 6, l = t & 63;
  const int wm = w & 1, wn = w >> 1;
  const int m0 = blockIdx.x * 64 + wm * 32;
  const int n0 = blockIdx.y * 128 + wn * 64;
  const int head = n0 >> 6;
  const int lr = l & 15, lk = l >> 4;
  const bf16* aBase = xbX + (size_t)(m0 >> 4) * 2048 + l * 8;
  const bf16* bBase = WtX + (size_t)(n0 >> 4) * 2048 + l * 8;
  f32x4 acc[2][4] = {};
  #pragma unroll
  for (int kc = 0; kc < 4; kc++) {
    short8 av0 = *reinterpret_cast<const short8*>(aBase + kc * 512);
    short8 av1 = *reinterpret_cast<const short8*>(aBase + 2048 + kc * 512);
    short8 bv0 = *reinterpret_cast<const short8*>(bBase + 0 * 2048 + kc * 512);
    short8 bv1 = *reinterpret_cast<const short8*>(bBase + 1 * 2048 + kc * 512);
    short8 bv2 = *reinterpret_cast<const short8*>(bBase + 2 * 2048 + kc * 512);
    short8 bv3 = *reinterpret_cast<const short8*>(bBase + 3 * 2048 + kc * 512);
    acc[0][0] = MFMA16(av0, bv0, acc[0][0]);
    acc[0][1] = MFMA16(av0, bv1, acc[0][1]);
    acc[0][2] = MFMA16(av0, bv2, acc[0][2]);
    acc[0][3] = MFMA16(av0, bv3, acc[0][3]);
    acc[1][0] = MFMA16(av1, bv0, acc[1][0]);
    acc[1][1] = MFMA16(av1, bv1, acc[1][1]);
    acc[1][2] = MFMA16(av1, bv2, acc[1][2]);
    acc[1][3] = MFMA16(av1, bv3, acc[1][3]);
  }
  float as_r[4], ad_r[4];
  #pragma unroll
  for (int ni = 0; ni < 4; ni++) {
    as_r[ni] = att_s[head * 64 + ni * 16 + lr];
    ad_r[ni] = att_d[head * 64 + ni * 16 + lr];
  }
  #pragma unroll
  for (int mi = 0; mi < 2; mi++) {
    #pragma unroll
    for (int r = 0; r < 4; r++) {
      int row = m0 + mi * 16 + lk * 4 + r;
      bool ok = row < M;
      float vs = 0.f, vd = 0.f;
      #pragma unroll
      for (int ni = 0; ni < 4; ni++) {
        float v = acc[mi][ni][r];
        vs += v * as_r[ni]; vd += v * ad_r[ni];
        if (ok) H1[(size_t)row * 512 + n0 + ni * 16 + lr] = __float2bfloat16(v);
      }
      vs += __shfl_xor(vs, 1); vs += __shfl_xor(vs, 2);
      vs += __shfl_xor(vs, 4); vs += __shfl_xor(vs, 8);
      vd += __shfl_xor(vd, 1); vd += __shfl_xor(vd, 2);
      vd += __shfl_xor(vd, 4); vd += __shfl_xor(vd, 8);
      if (ok && lr == 0) {
        a_src[(size_t)row * 8 + head] = vs;
        a_dst[(size_t)row * 8 + head] = vd;
      }
    }
  }
}

// ---------------- CSR build
__global__ __launch_bounds__(1024)
void scan_kernel(const int* __restrict__ deg, int* __restrict__ offs, int n) {
  __shared__ int sums[1024];
  int t = threadIdx.x;
  int chunk = (n + 1023) >> 10;
  int lo = t * chunk, hi = min(lo + chunk, n);
  int s = 0;
  for (int i = lo; i < hi; i++) s += deg[i];
  sums[t] = s;
  __syncthreads();
  for (int step = 1; step < 1024; step <<= 1) {
    int v = (t >= step) ? sums[t - step] : 0;
    __syncthreads();
    sums[t] += v;
    __syncthreads();
  }
  int run = (t == 0) ? 0 : sums[t - 1];
  for (int i = lo; i < hi; i++) { offs[i] = run; run += deg[i]; }
  if (t == 1023) offs[n] = sums[1023];
}

__global__ void scatter_kernel(const int* __restrict__ ei, const int* __restrict__ offs,
                               int* __restrict__ cursor, int* __restrict__ esrc, int E, int EP) {
  int e = blockIdx.x * blockDim.x + threadIdx.x;
  if (e >= EP) return;
  int s = (e < E) ? ei[e] : (e - E);
  int d = (e < E) ? ei[E + e] : (e - E);
  int pos = offs[d] + atomicAdd(&cursor[d], 1);
  esrc[pos] = s;
}

// ---------------- FUSED: gat1 softmax-aggregation + skip-folded h3 GEMV + att3 dots.
// One wave per node; lane l owns channels [8l, 8l+8). Register-only; no LDS, no barrier.
// Tail reduction = reduce-scatter tree (25 shuffles vs 96 butterfly).
__global__ __launch_bounds__(256)
void agg1_h3_kernel(const int* __restrict__ offs, const int* __restrict__ esrc,
                    const float* __restrict__ a_src1, const float* __restrict__ a_dst1,
                    const bf16* __restrict__ H1, const float* __restrict__ g1_b,
                    const float* __restrict__ X,
                    const float* __restrict__ W1pT, const float* __restrict__ W2pT,
                    const float* __restrict__ b3p,
                    const float* __restrict__ g3_as, const float* __restrict__ g3_ad,
                    float* __restrict__ H3, float* __restrict__ a3s, float* __restrict__ a3d,
                    int N) {
  const int l = threadIdx.x & 63;
  const int n = blockIdx.x * 4 + (threadIdx.x >> 6);
  if (n >= N) return;
  const int h = l >> 3;
  const float adh = a_dst1[n * 8 + h];
  const uint4* __restrict__ H1v = reinterpret_cast<const uint4*>(H1);
  const int lo = offs[n], hi = offs[n + 1];
  float acc[8] = {0.f, 0.f, 0.f, 0.f, 0.f, 0.f, 0.f, 0.f};
  float psum = 0.f;
  int i = lo;
  for (; i + 8 <= hi; i += 8) {          // 8 rows in flight
    int s0 = esrc[i+0], s1 = esrc[i+1], s2 = esrc[i+2], s3 = esrc[i+3];
    int s4 = esrc[i+4], s5 = esrc[i+5], s6 = esrc[i+6], s7 = esrc[i+7];
    float q0 = a_src1[s0*8+h], q1 = a_src1[s1*8+h], q2 = a_src1[s2*8+h], q3 = a_src1[s3*8+h];
    float q4 = a_src1[s4*8+h], q5 = a_src1[s5*8+h], q6 = a_src1[s6*8+h], q7 = a_src1[s7*8+h];
    uint4 r0 = H1v[(size_t)s0*64+l], r1 = H1v[(size_t)s1*64+l];
    uint4 r2 = H1v[(size_t)s2*64+l], r3 = H1v[(size_t)s3*64+l];
    uint4 r4 = H1v[(size_t)s4*64+l], r5 = H1v[(size_t)s5*64+l];
    uint4 r6 = H1v[(size_t)s6*64+l], r7 = H1v[(size_t)s7*64+l];
    float v0 = edge_w(q0, adh), v1 = edge_w(q1, adh), v2 = edge_w(q2, adh), v3 = edge_w(q3, adh);
    float v4 = edge_w(q4, adh), v5 = edge_w(q5, adh), v6 = edge_w(q6, adh), v7 = edge_w(q7, adh);
    psum += (v0 + v1 + v2 + v3) + (v4 + v5 + v6 + v7);
    accum_row(r0, v0, acc); accum_row(r1, v1, acc);
    accum_row(r2, v2, acc); accum_row(r3, v3, acc);
    accum_row(r4, v4, acc); accum_row(r5, v5, acc);
    accum_row(r6, v6, acc); accum_row(r7, v7, acc);
  }
  if (i + 4 <= hi) {
    int s0 = esrc[i+0], s1 = esrc[i+1], s2 = esrc[i+2], s3 = esrc[i+3];
    float q0 = a_src1[s0*8+h], q1 = a_src1[s1*8+h], q2 = a_src1[s2*8+h], q3 = a_src1[s3*8+h];
    uint4 r0 = H1v[(size_t)s0*64+l], r1 = H1v[(size_t)s1*64+l];
    uint4 r2 = H1v[(size_t)s2*64+l], r3 = H1v[(size_t)s3*64+l];
    float v0 = edge_w(q0, adh), v1 = edge_w(q1, adh), v2 = edge_w(q2, adh), v3 = edge_w(q3, adh);
    psum += v0 + v1 + v2 + v3;
    accum_row(r0, v0, acc); accum_row(r1, v1, acc);
    accum_row(r2, v2, acc); accum_row(r3, v3, acc);
    i += 4;
  }
  for (; i < hi; i++) {
    int s = esrc[i];
    float q = a_src1[(size_t)s*8+h];
    uint4 r = H1v[(size_t)s*64+l];
    float v = edge_w(q, adh);
    psum += v;
    accum_row(r, v, acc);
  }
  const float inv = 1.f / (psum + 1e-16f);
  float4 ba = *reinterpret_cast<const float4*>(&g1_b[l * 8]);
  float4 bb = *reinterpret_cast<const float4*>(&g1_b[l * 8 + 4]);
  float x1v[8];
  x1v[0] = acc[0]*inv + ba.x; x1v[1] = acc[1]*inv + ba.y;
  x1v[2] = acc[2]*inv + ba.z; x1v[3] = acc[3]*inv + ba.w;
  x1v[4] = acc[4]*inv + bb.x; x1v[5] = acc[5]*inv + bb.y;
  x1v[6] = acc[6]*inv + bb.z; x1v[7] = acc[7]*inv + bb.w;
  float2 xv = *reinterpret_cast<const float2*>(&X[(size_t)n * 128 + l * 2]);
  float p[16];
  #pragma unroll
  for (int j = 0; j < 16; j++) {
    float4 wa = *reinterpret_cast<const float4*>(&W2pT[j * 512 + l * 8]);
    float4 wb = *reinterpret_cast<const float4*>(&W2pT[j * 512 + l * 8 + 4]);
    float2 w1 = *reinterpret_cast<const float2*>(&W1pT[j * 128 + l * 2]);
    p[j] = x1v[0]*wa.x + x1v[1]*wa.y + x1v[2]*wa.z + x1v[3]*wa.w
         + x1v[4]*wb.x + x1v[5]*wb.y + x1v[6]*wb.z + x1v[7]*wb.w
         + xv.x*w1.x + xv.y*w1.y;
  }
  // ---- reduce-scatter tree: 16 values over 64 lanes -> value j on lane group (l>>2)==j
  float t8[8];
  #pragma unroll
  for (int k = 0; k < 8; k++) {
    float send = (l & 32) ? p[k] : p[k + 8];
    float keep = (l & 32) ? p[k + 8] : p[k];
    t8[k] = keep + __shfl_xor(send, 32);
  }
  float t4[4];
  #pragma unroll
  for (int k = 0; k < 4; k++) {
    float send = (l & 16) ? t8[k] : t8[k + 4];
    float keep = (l & 16) ? t8[k + 4] : t8[k];
    t4[k] = keep + __shfl_xor(send, 16);
  }
  float t2[2];
  #pragma unroll
  for (int k = 0; k < 2; k++) {
    float send = (l & 8) ? t2[0] : 0.f;  // placeholder; replaced below
    (void)send;
    float s2 = (l & 8) ? t4[k] : t4[k + 2];
    float k2 = (l & 8) ? t4[k + 2] : t4[k];
    t2[k] = k2 + __shfl_xor(s2, 8);
  }
  float t1;
  {
    float s1 = (l & 4) ? t2[0] : t2[1];
    float k1 = (l & 4) ? t2[1] : t2[0];
    t1 = k1 + __shfl_xor(s1, 4);
  }
  t1 += __shfl_xor(t1, 1);
  t1 += __shfl_xor(t1, 2);
  const int j2 = (l >> 2) & 15;          // which output this 4-lane group holds
  float o = t1 + b3p[j2];
  if ((l & 3) == 0) H3[(size_t)n * 16 + j2] = o;
  float vs = ((l & 3) == 0) ? o * g3_as[j2] : 0.f;
  float vd = ((l & 3) == 0) ? o * g3_ad[j2] : 0.f;
  vs += __shfl_xor(vs, 4); vs += __shfl_xor(vs, 8);
  vs += __shfl_xor(vs, 16); vs += __shfl_xor(vs, 32);
  vd += __shfl_xor(vd, 4); vd += __shfl_xor(vd, 8);
  vd += __shfl_xor(vd, 16); vd += __shfl_xor(vd, 32);
  if (l == 0) { a3s[n] = vs; a3d[n] = vd; }
}

// ---------------- gat3 aggregation -> d_out. Wave/node, 4 groups x 16 ch, unroll 4.
__global__ __launch_bounds__(256)
void agg3_kernel(const int* __restrict__ offs, const int* __restrict__ esrc,
                 const float* __restrict__ a3s, const float* __restrict__ a3d,
                 const float* __restrict__ H3, const float* __restrict__ g3_b,
                 float* __restrict__ out, int N) {
  const int l = threadIdx.x & 63;
  const int n = blockIdx.x * 4 + (threadIdx.x >> 6);
  if (n >= N) return;
  const int g = l >> 4, j = l & 15;
  const float ad = a3d[n];
  const int lo = offs[n], hi = offs[n + 1];
  float acc = 0.f, psum = 0.f;
  int i = lo + g;
  for (; i + 12 < hi; i += 16) {         // 4 edges in flight per lane-group
    int s0 = esrc[i], s1 = esrc[i + 4], s2 = esrc[i + 8], s3 = esrc[i + 12];
    float q0 = a3s[s0], q1 = a3s[s1], q2 = a3s[s2], q3 = a3s[s3];
    float h0 = H3[(size_t)s0 * 16 + j], h1 = H3[(size_t)s1 * 16 + j];
    float h2 = H3[(size_t)s2 * 16 + j], h3v = H3[(size_t)s3 * 16 + j];
    float v0 = edge_w(q0, ad), v1 = edge_w(q1, ad);
    float v2 = edge_w(q2, ad), v3 = edge_w(q3, ad);
    psum += (v0 + v1) + (v2 + v3);
    acc = fmaf(v0, h0, acc); acc = fmaf(v1, h1, acc);
    acc = fmaf(v2, h2, acc); acc = fmaf(v3, h3v, acc);
  }
  for (; i < hi; i += 4) {
    int s = esrc[i];
    float v = edge_w(a3s[s], ad);
    psum += v;
    acc = fmaf(v, H3[(size_t)s * 16 + j], acc);
  }
  acc += __shfl_xor(acc, 16);  acc += __shfl_xor(acc, 32);
  psum += __shfl_xor(psum, 16); psum += __shfl_xor(psum, 32);
  if (l < 16) out[(size_t)n * 16 + j] = acc / (psum + 1e-16f) + g3_b[j];
}

__global__ void sentinel_kernel(float* out) { out[threadIdx.x] = -1e9f; }

extern "C" void kernel_launch(void* const* d_in, const int* in_sizes, int n_in,
                              void* d_out, int out_size, void* d_ws, size_t ws_size,
                              hipStream_t stream) {
  const float* x      = (const float*)d_in[0];
  const int*   ei     = (const int*)d_in[1];
  const float* g1_W   = (const float*)d_in[2];
  const float* g1_as  = (const float*)d_in[3];
  const float* g1_ad  = (const float*)d_in[4];
  const float* g1_b   = (const float*)d_in[5];
  const float* sk1_W  = (const float*)d_in[6];
  const float* sk1_b  = (const float*)d_in[7];
  const float* sk2_W  = (const float*)d_in[8];
  const float* sk2_b  = (const float*)d_in[9];
  const float* g3_W   = (const float*)d_in[10];
  const float* g3_as  = (const float*)d_in[11];
  const float* g3_ad  = (const float*)d_in[12];
  const float* g3_b   = (const float*)d_in[13];
  float* out = (float*)d_out;

  const int N  = in_sizes[0] / 128;
  const int E  = in_sizes[1] / 2;
  const int EP = E + N;
  const int Mt = (N + 63) / 64;
  const int Np = Mt * 64;

  char* w = (char*)d_ws;
  size_t off = 0;
  auto alloc = [&](size_t bytes) -> void* {
    void* p = w + off;
    off = (off + bytes + 255) & ~(size_t)255;
    return p;
  };

  // zero-init block (single memset)
  int* deg    = (int*)alloc((size_t)N * 4);
  int* cursor = (int*)alloc((size_t)N * 4);
  size_t zbytes = off;
  // rest of workspace
  int*   offs   = (int*)alloc((size_t)(N + 1) * 4);
  int*   esrc   = (int*)alloc((size_t)EP * 4);
  bf16*  xbX    = (bf16*)alloc((size_t)Np * 128 * 2);
  bf16*  WtX    = (bf16*)alloc(512 * 128 * 2);
  bf16*  h1     = (bf16*)alloc((size_t)N * 512 * 2);
  float* a_src1 = (float*)alloc((size_t)N * 8 * 4);
  float* a_dst1 = (float*)alloc((size_t)N * 8 * 4);
  float* h3     = (float*)alloc((size_t)N * 16 * 4);
  float* a_src3 = (float*)alloc((size_t)N * 4);
  float* a_dst3 = (float*)alloc((size_t)N * 4);
  float* W1pT   = (float*)alloc(128 * 16 * 4);
  float* W2pT   = (float*)alloc(512 * 16 * 4);
  float* b3p    = (float*)alloc(16 * 4);
  (void)n_in; (void)out_size;

  if (off > ws_size) {  // workspace too small: fail loudly but safely
    sentinel_kernel<<<1, 16, 0, stream>>>(out);
    return;
  }

  hipMemsetAsync(d_ws, 0, zbytes, stream);

  const int eb = (EP + 255) / 256;
  const int nb4 = (N + 3) / 4;
  // setup partition: [0,bX) cast_x | [bX,bWT) cast_wt | w1p | w2p | b3p | deg
  const int bX = 1024, bWT = bX + 256, bW1 = bWT + 8, bW2 = bW1 + 32, bB3 = bW2 + 1;

  setup_kernel<<<bB3 + eb, 256, 0, stream>>>(
      x, ei, g1_W, sk1_W, sk1_b, sk2_W, sk2_b, g3_W,
      xbX, WtX, W1pT, W2pT, b3p, deg, N, Np, E, EP, bX, bWT, bW1, bW2, bB3);

  gemm_h1_kernel<<<dim3(Mt, 4), 256, 0, stream>>>(
      xbX, WtX, g1_as, g1_ad, h1, a_src1, a_dst1, N);

  scan_kernel<<<1, 1024, 0, stream>>>(deg, offs, N);
  scatter_kernel<<<eb, 256, 0, stream>>>(ei, offs, cursor, esrc, E, EP);

  agg1_h3_kernel<<<nb4, 256, 0, stream>>>(offs, esrc, a_src1, a_dst1, h1, g1_b, x,
                                          W1pT, W2pT, b3p, g3_as, g3_ad,
                                          h3, a_src3, a_dst3, N);

  agg3_kernel<<<nb4, 256, 0, stream>>>(offs, esrc, a_src3, a_dst3, h3, g3_b, out, N);
}

// Round 7
// 491.314 us; speedup vs baseline: 1.8122x; 1.1842x over previous
//
#include <hip/hip_runtime.h>
#include <hip/hip_bf16.h>

#define NEG_SLOPE 0.2f
using bf16 = __hip_bfloat16;

typedef __attribute__((ext_vector_type(8))) short short8;   // 8 bf16 (4 VGPRs)
typedef __attribute__((ext_vector_type(4))) float f32x4;
#define MFMA16(a, b, c) __builtin_amdgcn_mfma_f32_16x16x32_bf16(a, b, c, 0, 0, 0)

__device__ __forceinline__ float bflo(unsigned u) { return __uint_as_float(u << 16); }
__device__ __forceinline__ float bfhi(unsigned u) { return __uint_as_float(u & 0xffff0000u); }

__device__ __forceinline__ unsigned cvtpk(float lo, float hi) {
  unsigned r;
  asm volatile("v_cvt_pk_bf16_f32 %0, %1, %2" : "=v"(r) : "v"(lo), "v"(hi));
  return r;
}

__device__ __forceinline__ float edge_w(float q, float adh) {
  float t = q + adh;
  t = (t > 0.f) ? t : NEG_SLOPE * t;
  return __expf(t);
}

// MFMA-fragment packed offset: (tile, kc, lk, r, e) for 16-row tiles, K=128
__device__ __forceinline__ size_t frag_off(int row, int k) {
  return (size_t)(row >> 4) * 2048 + (k >> 5) * 512 + ((k >> 3) & 3) * 128 +
         (row & 15) * 8 + (k & 7);
}

// ---------------- fused setup: cast_x->xbX, cast_wt->WtX, w1p, w2p(+W2pSa frags), deg
__global__ __launch_bounds__(256)
void setup_kernel(const float* __restrict__ x, const int* __restrict__ ei,
                  const float* __restrict__ g1_W,
                  const float* __restrict__ sk1_W,
                  const float* __restrict__ sk2_W,
                  const float* __restrict__ g3_W,
                  bf16* __restrict__ xbX, bf16* __restrict__ WtX,
                  float* __restrict__ W1pT, float* __restrict__ W2pT,
                  bf16* __restrict__ W2pSa, int* __restrict__ deg,
                  int N, int Np, int E, int EP,
                  int bX, int bWT, int bW1, int bW2) {
  const int b = blockIdx.x;
  const int t = threadIdx.x;
  if (b < bX) {                       // x -> xbX (packed MFMA frag layout, zero pad)
    const int total4 = Np * 32;
    const int stride = bX * 256;
    for (int i = b * 256 + t; i < total4; i += stride) {
      int row = i >> 5, kq = (i & 31) * 4;
      float4 v = make_float4(0.f, 0.f, 0.f, 0.f);
      if (row < N) v = reinterpret_cast<const float4*>(x)[i];
      union { bf16 bv[4]; ushort4 u; } pk;
      pk.bv[0] = __float2bfloat16(v.x); pk.bv[1] = __float2bfloat16(v.y);
      pk.bv[2] = __float2bfloat16(v.z); pk.bv[3] = __float2bfloat16(v.w);
      *reinterpret_cast<ushort4*>(&xbX[frag_off(row, kq)]) = pk.u;
    }
  } else if (b < bWT) {               // g1_W -> WtX (packed MFMA frag layout)
    int i = (b - bX) * 256 + t;       // 65536 exactly
    int k = i >> 9, c = i & 511;
    WtX[frag_off(c, k)] = __float2bfloat16(g1_W[k * 512 + c]);
  } else if (b < bW1) {               // W1pT[16][128]
    int i = (b - bWT) * 256 + t;      // 2048
    int j = i >> 7, k = i & 127;
    float acc = 0.f;
    for (int m = 0; m < 512; m++) acc += sk1_W[k * 512 + m] * g3_W[m * 16 + j];
    W1pT[i] = acc;
  } else if (b < bW2) {               // W2pT[16][512] + packed A-frags W2pSa
    int i = (b - bW1) * 256 + t;      // 8192
    int j = i >> 9, c = i & 511;
    float acc = 0.f;
    for (int m = 0; m < 512; m++) acc += sk2_W[c * 512 + m] * g3_W[(512 + m) * 16 + j];
    W2pT[i] = acc;
    int h = c >> 6, cc = c & 63, kk = cc >> 5, lk = (cc >> 3) & 3, e = cc & 7;
    W2pSa[((size_t)(h * 2 + kk) * 64 + (j + 16 * lk)) * 8 + e] = __float2bfloat16(acc);
  } else {                            // degree histogram
    int e = (b - bW2) * 256 + t;
    if (e < EP) {
      int d = (e < E) ? ei[E + e] : (e - E);
      atomicAdd(&deg[d], 1);
    }
  }
}

// ---------------- setup2: b3p[j] = sk1_b@g3Wt + sk2_b@g3Wb + g1_b@W2p (needs W2pT)
__global__ __launch_bounds__(256)
void setup2_kernel(const float* __restrict__ sk1_b, const float* __restrict__ sk2_b,
                   const float* __restrict__ g1_b, const float* __restrict__ g3_W,
                   const float* __restrict__ W2pT, float* __restrict__ b3p) {
  __shared__ float red[16][16];
  int t = threadIdx.x;
  int j = t & 15, seg = t >> 4;
  float acc = 0.f;
  for (int m = seg * 32; m < seg * 32 + 32; m++)
    acc += sk1_b[m] * g3_W[m * 16 + j] + sk2_b[m] * g3_W[(512 + m) * 16 + j];
  for (int c = seg * 32; c < seg * 32 + 32; c++)
    acc += g1_b[c] * W2pT[j * 512 + c];
  red[seg][j] = acc;
  __syncthreads();
  if (t < 16) {
    float s = 0.f;
    for (int k = 0; k < 16; k++) s += red[k][t];
    b3p[t] = s;
  }
}

// ---------------- MFMA GEMM (swapped operands: acc = h1^T) + att dots + g1p projection.
// Block 256 thr = 4 waves (2M x 2N). Wave tile: 32 x-rows x 64 w-cols = 1 head.
// No H1 materialization: epilogue projects h1 tile to g1p[row][head][16j] via 4 MFMAs.
__global__ __launch_bounds__(256)
void gemm_h1_kernel(const bf16* __restrict__ xbX, const bf16* __restrict__ WtX,
                    const bf16* __restrict__ W2pSa,
                    const float* __restrict__ att_s, const float* __restrict__ att_d,
                    bf16* __restrict__ g1p, float* __restrict__ a_src, float* __restrict__ a_dst,
                    int M) {
  const int t = threadIdx.x;
  const int w = t >> 6, l = t & 63;
  const int wm = w & 1, wn = w >> 1;
  const int m0 = blockIdx.x * 64 + wm * 32;
  const int n0 = blockIdx.y * 128 + wn * 64;
  const int head = n0 >> 6;
  const int lr = l & 15, lk = l >> 4;
  const bf16* aBase = xbX + (size_t)(m0 >> 4) * 2048 + l * 8;
  const bf16* bBase = WtX + (size_t)(n0 >> 4) * 2048 + l * 8;
  f32x4 accT[4][2] = {};   // accT[ni][mi]: lane holds h1[xrow=mi*16+lr, wcol=ni*16+lk*4+r]
  #pragma unroll
  for (int kc = 0; kc < 4; kc++) {
    short8 av0 = *reinterpret_cast<const short8*>(aBase + kc * 512);
    short8 av1 = *reinterpret_cast<const short8*>(aBase + 2048 + kc * 512);
    short8 bv0 = *reinterpret_cast<const short8*>(bBase + 0 * 2048 + kc * 512);
    short8 bv1 = *reinterpret_cast<const short8*>(bBase + 1 * 2048 + kc * 512);
    short8 bv2 = *reinterpret_cast<const short8*>(bBase + 2 * 2048 + kc * 512);
    short8 bv3 = *reinterpret_cast<const short8*>(bBase + 3 * 2048 + kc * 512);
    accT[0][0] = MFMA16(bv0, av0, accT[0][0]);
    accT[1][0] = MFMA16(bv1, av0, accT[1][0]);
    accT[2][0] = MFMA16(bv2, av0, accT[2][0]);
    accT[3][0] = MFMA16(bv3, av0, accT[3][0]);
    accT[0][1] = MFMA16(bv0, av1, accT[0][1]);
    accT[1][1] = MFMA16(bv1, av1, accT[1][1]);
    accT[2][1] = MFMA16(bv2, av1, accT[2][1]);
    accT[3][1] = MFMA16(bv3, av1, accT[3][1]);
  }
  // ---- att dots: vs/vd per x-row (rows = mi*16+lr), cols spread over (ni, lk, r)
  #pragma unroll
  for (int mi = 0; mi < 2; mi++) {
    float vs = 0.f, vd = 0.f;
    #pragma unroll
    for (int ni = 0; ni < 4; ni++) {
      float4 as4 = *reinterpret_cast<const float4*>(&att_s[head * 64 + ni * 16 + lk * 4]);
      float4 ad4 = *reinterpret_cast<const float4*>(&att_d[head * 64 + ni * 16 + lk * 4]);
      vs += accT[ni][mi][0] * as4.x + accT[ni][mi][1] * as4.y +
            accT[ni][mi][2] * as4.z + accT[ni][mi][3] * as4.w;
      vd += accT[ni][mi][0] * ad4.x + accT[ni][mi][1] * ad4.y +
            accT[ni][mi][2] * ad4.z + accT[ni][mi][3] * ad4.w;
    }
    vs += __shfl_xor(vs, 16); vs += __shfl_xor(vs, 32);
    vd += __shfl_xor(vd, 16); vd += __shfl_xor(vd, 32);
    int row = m0 + mi * 16 + lr;
    if (lk == 0 && row < M) {
      a_src[(size_t)row * 8 + head] = vs;
      a_dst[(size_t)row * 8 + head] = vd;
    }
  }
  // ---- projection: g1p[row, head, j] = h1[row, head*64+c] @ W2p; D3 = W2pSa(16x64) x h1^T
  unsigned pk[4][2][2];
  #pragma unroll
  for (int ni = 0; ni < 4; ni++)
    #pragma unroll
    for (int mi = 0; mi < 2; mi++) {
      pk[ni][mi][0] = cvtpk(accT[ni][mi][0], accT[ni][mi][1]);
      pk[ni][mi][1] = cvtpk(accT[ni][mi][2], accT[ni][mi][3]);
    }
  f32x4 d3[2] = {};
  #pragma unroll
  for (int kk = 0; kk < 2; kk++) {
    short8 aw2 = *reinterpret_cast<const short8*>(&W2pSa[((size_t)(head * 2 + kk) * 64 + l) * 8]);
    #pragma unroll
    for (int mi = 0; mi < 2; mi++) {
      union { unsigned u[4]; short8 s8; } bf;
      #pragma unroll
      for (int v = 0; v < 4; v++) {
        int src = lr + 16 * ((lk & 1) * 2 + (v >> 1));
        unsigned t0 = __shfl(pk[2 * kk][mi][v & 1], src);
        unsigned t1 = __shfl(pk[2 * kk + 1][mi][v & 1], src);
        bf.u[v] = (lk & 2) ? t1 : t0;
      }
      d3[mi] = MFMA16(aw2, bf.s8, d3[mi]);
    }
  }
  #pragma unroll
  for (int mi = 0; mi < 2; mi++) {
    int row = m0 + mi * 16 + lr;           // d3[mi]: col=lr=xrow, j=lk*4+reg
    if (row < M) {
      uint2 st;
      st.x = cvtpk(d3[mi][0], d3[mi][1]);
      st.y = cvtpk(d3[mi][2], d3[mi][3]);
      *reinterpret_cast<uint2*>(&g1p[(size_t)row * 128 + head * 16 + lk * 4]) = st;
    }
  }
}

// ---------------- CSR build
__global__ __launch_bounds__(1024)
void scan_kernel(const int* __restrict__ deg, int* __restrict__ offs, int n) {
  __shared__ int sums[1024];
  int t = threadIdx.x;
  int chunk = (n + 1023) >> 10;
  int lo = t * chunk, hi = min(lo + chunk, n);
  int s = 0;
  for (int i = lo; i < hi; i++) s += deg[i];
  sums[t] = s;
  __syncthreads();
  for (int step = 1; step < 1024; step <<= 1) {
    int v = (t >= step) ? sums[t - step] : 0;
    __syncthreads();
    sums[t] += v;
    __syncthreads();
  }
  int run = (t == 0) ? 0 : sums[t - 1];
  for (int i = lo; i < hi; i++) { offs[i] = run; run += deg[i]; }
  if (t == 1023) offs[n] = sums[1023];
}

__global__ void scatter_kernel(const int* __restrict__ ei, const int* __restrict__ offs,
                               int* __restrict__ cursor, int* __restrict__ esrc, int E, int EP) {
  int e = blockIdx.x * blockDim.x + threadIdx.x;
  if (e >= EP) return;
  int s = (e < E) ? ei[e] : (e - E);
  int d = (e < E) ? ei[E + e] : (e - E);
  int pos = offs[d] + atomicAdd(&cursor[d], 1);
  esrc[pos] = s;
}

// ---------------- FUSED: gat1 softmax-agg over PROJECTED g1p (256B/edge) + x@W1p + att3.
// One wave per node; lane l = (g = l>>3 head, j0 = l&7 j-pair). Register-only.
__global__ __launch_bounds__(256)
void agg1_h3_kernel(const int* __restrict__ offs, const int* __restrict__ esrc,
                    const float* __restrict__ a_src1, const float* __restrict__ a_dst1,
                    const bf16* __restrict__ g1p,
                    const float* __restrict__ X,
                    const float* __restrict__ W1pT, const float* __restrict__ b3p,
                    const float* __restrict__ g3_as, const float* __restrict__ g3_ad,
                    bf16* __restrict__ H3b, float* __restrict__ a3s, float* __restrict__ a3d,
                    int N) {
  const int l = threadIdx.x & 63;
  const int n = blockIdx.x * 4 + (threadIdx.x >> 6);
  if (n >= N) return;
  const int g = l >> 3, j0 = l & 7;
  const float adh = a_dst1[n * 8 + g];
  const unsigned* __restrict__ G = reinterpret_cast<const unsigned*>(g1p);  // 64 u32/row
  const int lo = offs[n], hi = offs[n + 1];
  const int gj = g * 8 + j0;
  float agg0 = 0.f, agg1 = 0.f, psum = 0.f;
  int i = lo;
  for (; i + 8 <= hi; i += 8) {
    int s0 = esrc[i+0], s1 = esrc[i+1], s2 = esrc[i+2], s3 = esrc[i+3];
    int s4 = esrc[i+4], s5 = esrc[i+5], s6 = esrc[i+6], s7 = esrc[i+7];
    float q0 = a_src1[s0*8+g], q1 = a_src1[s1*8+g], q2 = a_src1[s2*8+g], q3 = a_src1[s3*8+g];
    float q4 = a_src1[s4*8+g], q5 = a_src1[s5*8+g], q6 = a_src1[s6*8+g], q7 = a_src1[s7*8+g];
    unsigned w0 = G[(size_t)s0*64+gj], w1 = G[(size_t)s1*64+gj];
    unsigned w2 = G[(size_t)s2*64+gj], w3 = G[(size_t)s3*64+gj];
    unsigned w4 = G[(size_t)s4*64+gj], w5 = G[(size_t)s5*64+gj];
    unsigned w6 = G[(size_t)s6*64+gj], w7 = G[(size_t)s7*64+gj];
    float v0 = edge_w(q0, adh), v1 = edge_w(q1, adh), v2 = edge_w(q2, adh), v3 = edge_w(q3, adh);
    float v4 = edge_w(q4, adh), v5 = edge_w(q5, adh), v6 = edge_w(q6, adh), v7 = edge_w(q7, adh);
    psum += (v0 + v1 + v2 + v3) + (v4 + v5 + v6 + v7);
    agg0 = fmaf(v0, bflo(w0), agg0); agg1 = fmaf(v0, bfhi(w0), agg1);
    agg0 = fmaf(v1, bflo(w1), agg0); agg1 = fmaf(v1, bfhi(w1), agg1);
    agg0 = fmaf(v2, bflo(w2), agg0); agg1 = fmaf(v2, bfhi(w2), agg1);
    agg0 = fmaf(v3, bflo(w3), agg0); agg1 = fmaf(v3, bfhi(w3), agg1);
    agg0 = fmaf(v4, bflo(w4), agg0); agg1 = fmaf(v4, bfhi(w4), agg1);
    agg0 = fmaf(v5, bflo(w5), agg0); agg1 = fmaf(v5, bfhi(w5), agg1);
    agg0 = fmaf(v6, bflo(w6), agg0); agg1 = fmaf(v6, bfhi(w6), agg1);
    agg0 = fmaf(v7, bflo(w7), agg0); agg1 = fmaf(v7, bfhi(w7), agg1);
  }
  for (; i < hi; i++) {
    int s = esrc[i];
    float q = a_src1[(size_t)s * 8 + g];
    unsigned w0 = G[(size_t)s * 64 + gj];
    float v = edge_w(q, adh);
    psum += v;
    agg0 = fmaf(v, bflo(w0), agg0); agg1 = fmaf(v, bfhi(w0), agg1);
  }
  const float inv = 1.f / (psum + 1e-16f);
  float v0 = agg0 * inv, v1 = agg1 * inv;
  // x @ W1p: lane covers x-chunk [g*16, g*16+16) for its 2 j's
  {
    const float* xr = &X[(size_t)n * 128 + g * 16];
    const float* wr0 = &W1pT[(2 * j0) * 128 + g * 16];
    const float* wr1 = &W1pT[(2 * j0 + 1) * 128 + g * 16];
    #pragma unroll
    for (int c = 0; c < 16; c += 4) {
      float4 xa = *reinterpret_cast<const float4*>(xr + c);
      float4 wa = *reinterpret_cast<const float4*>(wr0 + c);
      float4 wb = *reinterpret_cast<const float4*>(wr1 + c);
      v0 += xa.x * wa.x + xa.y * wa.y + xa.z * wa.z + xa.w * wa.w;
      v1 += xa.x * wb.x + xa.y * wb.y + xa.z * wb.z + xa.w * wb.w;
    }
  }
  v0 += __shfl_xor(v0, 8); v0 += __shfl_xor(v0, 16); v0 += __shfl_xor(v0, 32);
  v1 += __shfl_xor(v1, 8); v1 += __shfl_xor(v1, 16); v1 += __shfl_xor(v1, 32);
  float o0 = v0 + b3p[2 * j0];
  float o1 = v1 + b3p[2 * j0 + 1];
  if (g == 0) reinterpret_cast<unsigned*>(H3b)[(size_t)n * 8 + j0] = cvtpk(o0, o1);
  float vs = o0 * g3_as[2 * j0] + o1 * g3_as[2 * j0 + 1];
  float vd = o0 * g3_ad[2 * j0] + o1 * g3_ad[2 * j0 + 1];
  vs += __shfl_xor(vs, 1); vs += __shfl_xor(vs, 2); vs += __shfl_xor(vs, 4);
  vd += __shfl_xor(vd, 1); vd += __shfl_xor(vd, 2); vd += __shfl_xor(vd, 4);
  if (l == 0) { a3s[n] = vs; a3d[n] = vd; }
}

// ---------------- gat3 aggregation (bf16 H3) -> d_out. Wave/node, 4 groups x 16 ch.
__global__ __launch_bounds__(256)
void agg3_kernel(const int* __restrict__ offs, const int* __restrict__ esrc,
                 const float* __restrict__ a3s, const float* __restrict__ a3d,
                 const bf16* __restrict__ H3b, const float* __restrict__ g3_b,
                 float* __restrict__ out, int N) {
  const int l = threadIdx.x & 63;
  const int n = blockIdx.x * 4 + (threadIdx.x >> 6);
  if (n >= N) return;
  const int g = l >> 4, j = l & 15;
  const float ad = a3d[n];
  const ushort* __restrict__ H = reinterpret_cast<const ushort*>(H3b);
  const int lo = offs[n], hi = offs[n + 1];
  float acc = 0.f, psum = 0.f;
  int i = lo + g;
  for (; i + 12 < hi; i += 16) {
    int s0 = esrc[i], s1 = esrc[i + 4], s2 = esrc[i + 8], s3 = esrc[i + 12];
    float q0 = a3s[s0], q1 = a3s[s1], q2 = a3s[s2], q3 = a3s[s3];
    float h0 = bflo((unsigned)H[(size_t)s0 * 16 + j] << 16 >> 16 | ((unsigned)H[(size_t)s0 * 16 + j] << 16));
    // (unpack below instead — keep simple)
    h0 = __uint_as_float((unsigned)H[(size_t)s0 * 16 + j] << 16);
    float h1 = __uint_as_float((unsigned)H[(size_t)s1 * 16 + j] << 16);
    float h2 = __uint_as_float((unsigned)H[(size_t)s2 * 16 + j] << 16);
    float h3v = __uint_as_float((unsigned)H[(size_t)s3 * 16 + j] << 16);
    float v0 = edge_w(q0, ad), v1 = edge_w(q1, ad);
    float v2 = edge_w(q2, ad), v3 = edge_w(q3, ad);
    psum += (v0 + v1) + (v2 + v3);
    acc = fmaf(v0, h0, acc); acc = fmaf(v1, h1, acc);
    acc = fmaf(v2, h2, acc); acc = fmaf(v3, h3v, acc);
  }
  for (; i < hi; i += 4) {
    int s = esrc[i];
    float v = edge_w(a3s[s], ad);
    psum += v;
    acc = fmaf(v, __uint_as_float((unsigned)H[(size_t)s * 16 + j] << 16), acc);
  }
  acc += __shfl_xor(acc, 16);  acc += __shfl_xor(acc, 32);
  psum += __shfl_xor(psum, 16); psum += __shfl_xor(psum, 32);
  if (l < 16) out[(size_t)n * 16 + j] = acc / (psum + 1e-16f) + g3_b[j];
}

__global__ void sentinel_kernel(float* out) { out[threadIdx.x] = -1e9f; }

extern "C" void kernel_launch(void* const* d_in, const int* in_sizes, int n_in,
                              void* d_out, int out_size, void* d_ws, size_t ws_size,
                              hipStream_t stream) {
  const float* x      = (const float*)d_in[0];
  const int*   ei     = (const int*)d_in[1];
  const float* g1_W   = (const float*)d_in[2];
  const float* g1_as  = (const float*)d_in[3];
  const float* g1_ad  = (const float*)d_in[4];
  const float* g1_b   = (const float*)d_in[5];
  const float* sk1_W  = (const float*)d_in[6];
  const float* sk1_b  = (const float*)d_in[7];
  const float* sk2_W  = (const float*)d_in[8];
  const float* sk2_b  = (const float*)d_in[9];
  const float* g3_W   = (const float*)d_in[10];
  const float* g3_as  = (const float*)d_in[11];
  const float* g3_ad  = (const float*)d_in[12];
  const float* g3_b   = (const float*)d_in[13];
  float* out = (float*)d_out;

  const int N  = in_sizes[0] / 128;
  const int E  = in_sizes[1] / 2;
  const int EP = E + N;
  const int Mt = (N + 63) / 64;
  const int Np = Mt * 64;

  char* w = (char*)d_ws;
  size_t off = 0;
  auto alloc = [&](size_t bytes) -> void* {
    void* p = w + off;
    off = (off + bytes + 255) & ~(size_t)255;
    return p;
  };

  // zero-init block (single memset)
  int* deg    = (int*)alloc((size_t)N * 4);
  int* cursor = (int*)alloc((size_t)N * 4);
  size_t zbytes = off;
  // rest of workspace
  int*   offs   = (int*)alloc((size_t)(N + 1) * 4);
  int*   esrc   = (int*)alloc((size_t)EP * 4);
  bf16*  xbX    = (bf16*)alloc((size_t)Np * 128 * 2);
  bf16*  WtX    = (bf16*)alloc(512 * 128 * 2);
  bf16*  W2pSa  = (bf16*)alloc(8192 * 2);
  bf16*  g1p    = (bf16*)alloc((size_t)N * 128 * 2);
  float* a_src1 = (float*)alloc((size_t)N * 8 * 4);
  float* a_dst1 = (float*)alloc((size_t)N * 8 * 4);
  bf16*  h3b    = (bf16*)alloc((size_t)N * 16 * 2);
  float* a_src3 = (float*)alloc((size_t)N * 4);
  float* a_dst3 = (float*)alloc((size_t)N * 4);
  float* W1pT   = (float*)alloc(128 * 16 * 4);
  float* W2pT   = (float*)alloc(512 * 16 * 4);
  float* b3p    = (float*)alloc(16 * 4);
  (void)n_in; (void)out_size;

  if (off > ws_size) {  // workspace too small: fail loudly but safely
    sentinel_kernel<<<1, 16, 0, stream>>>(out);
    return;
  }

  hipMemsetAsync(d_ws, 0, zbytes, stream);

  const int eb = (EP + 255) / 256;
  const int nb4 = (N + 3) / 4;
  // setup partition: [0,bX) cast_x | [bX,bWT) cast_wt | w1p | w2p | deg
  const int bX = 1024, bWT = bX + 256, bW1 = bWT + 8, bW2 = bW1 + 32;

  setup_kernel<<<bW2 + eb, 256, 0, stream>>>(
      x, ei, g1_W, sk1_W, sk2_W, g3_W,
      xbX, WtX, W1pT, W2pT, W2pSa, deg, N, Np, E, EP, bX, bWT, bW1, bW2);
  setup2_kernel<<<1, 256, 0, stream>>>(sk1_b, sk2_b, g1_b, g3_W, W2pT, b3p);

  gemm_h1_kernel<<<dim3(Mt, 4), 256, 0, stream>>>(
      xbX, WtX, W2pSa, g1_as, g1_ad, g1p, a_src1, a_dst1, N);

  scan_kernel<<<1, 1024, 0, stream>>>(deg, offs, N);
  scatter_kernel<<<eb, 256, 0, stream>>>(ei, offs, cursor, esrc, E, EP);

  agg1_h3_kernel<<<nb4, 256, 0, stream>>>(offs, esrc, a_src1, a_dst1, g1p, x,
                                          W1pT, b3p, g3_as, g3_ad,
                                          h3b, a_src3, a_dst3, N);

  agg3_kernel<<<nb4, 256, 0, stream>>>(offs, esrc, a_src3, a_dst3, h3b, g3_b, out, N);
}

// Round 8
// 342.706 us; speedup vs baseline: 2.5980x; 1.4336x over previous
//
#include <hip/hip_runtime.h>
#include <hip/hip_bf16.h>

#define NEG_SLOPE 0.2f
using bf16 = __hip_bfloat16;

typedef __attribute__((ext_vector_type(8))) short short8;   // 8 bf16 (4 VGPRs)
typedef __attribute__((ext_vector_type(4))) float f32x4;
#define MFMA16(a, b, c) __builtin_amdgcn_mfma_f32_16x16x32_bf16(a, b, c, 0, 0, 0)

__device__ __forceinline__ float bflo(unsigned u) { return __uint_as_float(u << 16); }
__device__ __forceinline__ float bfhi(unsigned u) { return __uint_as_float(u & 0xffff0000u); }

__device__ __forceinline__ unsigned cvtpk(float lo, float hi) {
  unsigned r;
  asm volatile("v_cvt_pk_bf16_f32 %0, %1, %2" : "=v"(r) : "v"(lo), "v"(hi));
  return r;
}

__device__ __forceinline__ float edge_w(float q, float adh) {
  float t = q + adh;
  t = (t > 0.f) ? t : NEG_SLOPE * t;
  return __expf(t);
}

// MFMA-fragment packed offset: (tile, kc, lk, r, e) for 16-row tiles, K=128
__device__ __forceinline__ size_t frag_off(int row, int k) {
  return (size_t)(row >> 4) * 2048 + (k >> 5) * 512 + ((k >> 3) & 3) * 128 +
         (row & 15) * 8 + (k & 7);
}

// ---------------- fused setup: cast_x->xbX, cast_wt->WtX, w1p, w2p(+W2pSa frags), deg
__global__ __launch_bounds__(256)
void setup_kernel(const float* __restrict__ x, const int* __restrict__ ei,
                  const float* __restrict__ g1_W,
                  const float* __restrict__ sk1_W,
                  const float* __restrict__ sk2_W,
                  const float* __restrict__ g3_W,
                  bf16* __restrict__ xbX, bf16* __restrict__ WtX,
                  float* __restrict__ W1pT, float* __restrict__ W2pT,
                  bf16* __restrict__ W2pSa, int* __restrict__ deg,
                  int N, int Np, int E, int EP,
                  int bX, int bWT, int bW1, int bW2) {
  const int b = blockIdx.x;
  const int t = threadIdx.x;
  if (b < bX) {                       // x -> xbX (packed MFMA frag layout, zero pad)
    const int total4 = Np * 32;
    const int stride = bX * 256;
    for (int i = b * 256 + t; i < total4; i += stride) {
      int row = i >> 5, kq = (i & 31) * 4;
      float4 v = make_float4(0.f, 0.f, 0.f, 0.f);
      if (row < N) v = reinterpret_cast<const float4*>(x)[i];
      union { bf16 bv[4]; ushort4 u; } pk;
      pk.bv[0] = __float2bfloat16(v.x); pk.bv[1] = __float2bfloat16(v.y);
      pk.bv[2] = __float2bfloat16(v.z); pk.bv[3] = __float2bfloat16(v.w);
      *reinterpret_cast<ushort4*>(&xbX[frag_off(row, kq)]) = pk.u;
    }
  } else if (b < bWT) {               // g1_W -> WtX (packed MFMA frag layout)
    int i = (b - bX) * 256 + t;       // 65536 exactly
    int k = i >> 9, c = i & 511;
    WtX[frag_off(c, k)] = __float2bfloat16(g1_W[k * 512 + c]);
  } else if (b < bW1) {               // W1pT[16][128]
    int i = (b - bWT) * 256 + t;      // 2048
    int j = i >> 7, k = i & 127;
    float acc = 0.f;
    for (int m = 0; m < 512; m++) acc += sk1_W[k * 512 + m] * g3_W[m * 16 + j];
    W1pT[i] = acc;
  } else if (b < bW2) {               // W2pT[16][512] + packed A-frags W2pSa
    int i = (b - bW1) * 256 + t;      // 8192
    int j = i >> 9, c = i & 511;
    float acc = 0.f;
    for (int m = 0; m < 512; m++) acc += sk2_W[c * 512 + m] * g3_W[(512 + m) * 16 + j];
    W2pT[i] = acc;
    int h = c >> 6, cc = c & 63, kk = cc >> 5, lk = (cc >> 3) & 3, e = cc & 7;
    W2pSa[((size_t)(h * 2 + kk) * 64 + (j + 16 * lk)) * 8 + e] = __float2bfloat16(acc);
  } else {                            // degree histogram
    int e = (b - bW2) * 256 + t;
    if (e < EP) {
      int d = (e < E) ? ei[E + e] : (e - E);
      atomicAdd(&deg[d], 1);
    }
  }
}

// ---------------- setup2: b3p[j] = sk1_b@g3Wt + sk2_b@g3Wb + g1_b@W2p (needs W2pT)
__global__ __launch_bounds__(256)
void setup2_kernel(const float* __restrict__ sk1_b, const float* __restrict__ sk2_b,
                   const float* __restrict__ g1_b, const float* __restrict__ g3_W,
                   const float* __restrict__ W2pT, float* __restrict__ b3p) {
  __shared__ float red[16][16];
  int t = threadIdx.x;
  int j = t & 15, seg = t >> 4;
  float acc = 0.f;
  for (int m = seg * 32; m < seg * 32 + 32; m++)
    acc += sk1_b[m] * g3_W[m * 16 + j] + sk2_b[m] * g3_W[(512 + m) * 16 + j];
  for (int c = seg * 32; c < seg * 32 + 32; c++)
    acc += g1_b[c] * W2pT[j * 512 + c];
  red[seg][j] = acc;
  __syncthreads();
  if (t < 16) {
    float s = 0.f;
    for (int k = 0; k < 16; k++) s += red[k][t];
    b3p[t] = s;
  }
}

// ---------------- MFMA GEMM (swapped operands: acc = h1^T) + att dots + g1p projection.
__global__ __launch_bounds__(256)
void gemm_h1_kernel(const bf16* __restrict__ xbX, const bf16* __restrict__ WtX,
                    const bf16* __restrict__ W2pSa,
                    const float* __restrict__ att_s, const float* __restrict__ att_d,
                    bf16* __restrict__ g1p, float* __restrict__ a_src, float* __restrict__ a_dst,
                    int M) {
  const int t = threadIdx.x;
  const int w = t >> 6, l = t & 63;
  const int wm = w & 1, wn = w >> 1;
  const int m0 = blockIdx.x * 64 + wm * 32;
  const int n0 = blockIdx.y * 128 + wn * 64;
  const int head = n0 >> 6;
  const int lr = l & 15, lk = l >> 4;
  const bf16* aBase = xbX + (size_t)(m0 >> 4) * 2048 + l * 8;
  const bf16* bBase = WtX + (size_t)(n0 >> 4) * 2048 + l * 8;
  f32x4 accT[4][2] = {};   // accT[ni][mi]: lane holds h1[xrow=mi*16+lr, wcol=ni*16+lk*4+r]
  #pragma unroll
  for (int kc = 0; kc < 4; kc++) {
    short8 av0 = *reinterpret_cast<const short8*>(aBase + kc * 512);
    short8 av1 = *reinterpret_cast<const short8*>(aBase + 2048 + kc * 512);
    short8 bv0 = *reinterpret_cast<const short8*>(bBase + 0 * 2048 + kc * 512);
    short8 bv1 = *reinterpret_cast<const short8*>(bBase + 1 * 2048 + kc * 512);
    short8 bv2 = *reinterpret_cast<const short8*>(bBase + 2 * 2048 + kc * 512);
    short8 bv3 = *reinterpret_cast<const short8*>(bBase + 3 * 2048 + kc * 512);
    accT[0][0] = MFMA16(bv0, av0, accT[0][0]);
    accT[1][0] = MFMA16(bv1, av0, accT[1][0]);
    accT[2][0] = MFMA16(bv2, av0, accT[2][0]);
    accT[3][0] = MFMA16(bv3, av0, accT[3][0]);
    accT[0][1] = MFMA16(bv0, av1, accT[0][1]);
    accT[1][1] = MFMA16(bv1, av1, accT[1][1]);
    accT[2][1] = MFMA16(bv2, av1, accT[2][1]);
    accT[3][1] = MFMA16(bv3, av1, accT[3][1]);
  }
  #pragma unroll
  for (int mi = 0; mi < 2; mi++) {
    float vs = 0.f, vd = 0.f;
    #pragma unroll
    for (int ni = 0; ni < 4; ni++) {
      float4 as4 = *reinterpret_cast<const float4*>(&att_s[head * 64 + ni * 16 + lk * 4]);
      float4 ad4 = *reinterpret_cast<const float4*>(&att_d[head * 64 + ni * 16 + lk * 4]);
      vs += accT[ni][mi][0] * as4.x + accT[ni][mi][1] * as4.y +
            accT[ni][mi][2] * as4.z + accT[ni][mi][3] * as4.w;
      vd += accT[ni][mi][0] * ad4.x + accT[ni][mi][1] * ad4.y +
            accT[ni][mi][2] * ad4.z + accT[ni][mi][3] * ad4.w;
    }
    vs += __shfl_xor(vs, 16); vs += __shfl_xor(vs, 32);
    vd += __shfl_xor(vd, 16); vd += __shfl_xor(vd, 32);
    int row = m0 + mi * 16 + lr;
    if (lk == 0 && row < M) {
      a_src[(size_t)row * 8 + head] = vs;
      a_dst[(size_t)row * 8 + head] = vd;
    }
  }
  unsigned pk[4][2][2];
  #pragma unroll
  for (int ni = 0; ni < 4; ni++)
    #pragma unroll
    for (int mi = 0; mi < 2; mi++) {
      pk[ni][mi][0] = cvtpk(accT[ni][mi][0], accT[ni][mi][1]);
      pk[ni][mi][1] = cvtpk(accT[ni][mi][2], accT[ni][mi][3]);
    }
  f32x4 d3[2] = {};
  #pragma unroll
  for (int kk = 0; kk < 2; kk++) {
    short8 aw2 = *reinterpret_cast<const short8*>(&W2pSa[((size_t)(head * 2 + kk) * 64 + l) * 8]);
    #pragma unroll
    for (int mi = 0; mi < 2; mi++) {
      union { unsigned u[4]; short8 s8; } bf;
      #pragma unroll
      for (int v = 0; v < 4; v++) {
        int src = lr + 16 * ((lk & 1) * 2 + (v >> 1));
        unsigned t0 = __shfl(pk[2 * kk][mi][v & 1], src);
        unsigned t1 = __shfl(pk[2 * kk + 1][mi][v & 1], src);
        bf.u[v] = (lk & 2) ? t1 : t0;
      }
      d3[mi] = MFMA16(aw2, bf.s8, d3[mi]);
    }
  }
  #pragma unroll
  for (int mi = 0; mi < 2; mi++) {
    int row = m0 + mi * 16 + lr;           // d3[mi]: col=lr=xrow, j=lk*4+reg
    if (row < M) {
      uint2 st;
      st.x = cvtpk(d3[mi][0], d3[mi][1]);
      st.y = cvtpk(d3[mi][2], d3[mi][3]);
      *reinterpret_cast<uint2*>(&g1p[(size_t)row * 128 + head * 16 + lk * 4]) = st;
    }
  }
}

// ---------------- CSR build: 3-phase multi-block exclusive scan
// scan1: per-block (1024-elem chunk) exclusive scan of deg -> offs, block total -> bsum
__global__ __launch_bounds__(256)
void scan1_kernel(const int* __restrict__ deg, int* __restrict__ offs,
                  int* __restrict__ bsum, int n) {
  __shared__ int ts[256];
  const int b = blockIdx.x, t = threadIdx.x;
  const int base = b * 1024 + t * 4;
  int4 v = make_int4(0, 0, 0, 0);
  if (base + 3 < n) v = *reinterpret_cast<const int4*>(&deg[base]);
  else {
    if (base + 0 < n) v.x = deg[base + 0];
    if (base + 1 < n) v.y = deg[base + 1];
    if (base + 2 < n) v.z = deg[base + 2];
  }
  ts[t] = v.x + v.y + v.z + v.w;
  __syncthreads();
  for (int st = 1; st < 256; st <<= 1) {
    int u = (t >= st) ? ts[t - st] : 0;
    __syncthreads();
    ts[t] += u;
    __syncthreads();
  }
  int excl = (t == 0) ? 0 : ts[t - 1];
  int4 o;
  o.x = excl;
  o.y = o.x + v.x;
  o.z = o.y + v.y;
  o.w = o.z + v.z;
  if (base + 3 < n) *reinterpret_cast<int4*>(&offs[base]) = o;
  else {
    if (base + 0 < n) offs[base + 0] = o.x;
    if (base + 1 < n) offs[base + 1] = o.y;
    if (base + 2 < n) offs[base + 2] = o.z;
  }
  if (t == 255) bsum[b] = ts[255];
}

// scan2: exclusive scan of block sums (in place), total -> offs[n]
__global__ __launch_bounds__(256)
void scan2_kernel(int* __restrict__ bsum, int nb, int* __restrict__ offs, int n) {
  __shared__ int ts[256];
  const int t = threadIdx.x;
  const int c = (nb + 255) >> 8;
  const int lo = t * c, hi = min(lo + c, nb);
  int s = 0;
  for (int i = lo; i < hi; i++) s += bsum[i];
  ts[t] = s;
  __syncthreads();
  for (int st = 1; st < 256; st <<= 1) {
    int u = (t >= st) ? ts[t - st] : 0;
    __syncthreads();
    ts[t] += u;
    __syncthreads();
  }
  int run = (t == 0) ? 0 : ts[t - 1];
  for (int i = lo; i < hi; i++) { int v = bsum[i]; bsum[i] = run; run += v; }
  if (t == 255) offs[n] = ts[255];
}

// scan3: offs[chunk b] += bsum[b]
__global__ __launch_bounds__(256)
void scan3_kernel(int* __restrict__ offs, const int* __restrict__ bsum, int n) {
  const int b = blockIdx.x, t = threadIdx.x;
  const int base = b * 1024 + t * 4;
  const int add = bsum[b];
  if (add == 0) return;
  if (base + 3 < n) {
    int4 o = *reinterpret_cast<const int4*>(&offs[base]);
    o.x += add; o.y += add; o.z += add; o.w += add;
    *reinterpret_cast<int4*>(&offs[base]) = o;
  } else {
    if (base + 0 < n) offs[base + 0] += add;
    if (base + 1 < n) offs[base + 1] += add;
    if (base + 2 < n) offs[base + 2] += add;
  }
}

__global__ void scatter_kernel(const int* __restrict__ ei, const int* __restrict__ offs,
                               int* __restrict__ cursor, int* __restrict__ esrc, int E, int EP) {
  int e = blockIdx.x * blockDim.x + threadIdx.x;
  if (e >= EP) return;
  int s = (e < E) ? ei[e] : (e - E);
  int d = (e < E) ? ei[E + e] : (e - E);
  int pos = offs[d] + atomicAdd(&cursor[d], 1);
  esrc[pos] = s;
}

// ---------------- FUSED: gat1 softmax-agg over PROJECTED g1p (256B/edge) + x@W1p + att3.
__global__ __launch_bounds__(256)
void agg1_h3_kernel(const int* __restrict__ offs, const int* __restrict__ esrc,
                    const float* __restrict__ a_src1, const float* __restrict__ a_dst1,
                    const bf16* __restrict__ g1p,
                    const float* __restrict__ X,
                    const float* __restrict__ W1pT, const float* __restrict__ b3p,
                    const float* __restrict__ g3_as, const float* __restrict__ g3_ad,
                    bf16* __restrict__ H3b, float* __restrict__ a3s, float* __restrict__ a3d,
                    int N) {
  const int l = threadIdx.x & 63;
  const int n = blockIdx.x * 4 + (threadIdx.x >> 6);
  if (n >= N) return;
  const int g = l >> 3, j0 = l & 7;
  const float adh = a_dst1[n * 8 + g];
  const unsigned* __restrict__ G = reinterpret_cast<const unsigned*>(g1p);  // 64 u32/row
  const int lo = offs[n], hi = offs[n + 1];
  const int gj = g * 8 + j0;
  float agg0 = 0.f, agg1 = 0.f, psum = 0.f;
  int i = lo;
  for (; i + 8 <= hi; i += 8) {
    int s0 = esrc[i+0], s1 = esrc[i+1], s2 = esrc[i+2], s3 = esrc[i+3];
    int s4 = esrc[i+4], s5 = esrc[i+5], s6 = esrc[i+6], s7 = esrc[i+7];
    float q0 = a_src1[s0*8+g], q1 = a_src1[s1*8+g], q2 = a_src1[s2*8+g], q3 = a_src1[s3*8+g];
    float q4 = a_src1[s4*8+g], q5 = a_src1[s5*8+g], q6 = a_src1[s6*8+g], q7 = a_src1[s7*8+g];
    unsigned w0 = G[(size_t)s0*64+gj], w1 = G[(size_t)s1*64+gj];
    unsigned w2 = G[(size_t)s2*64+gj], w3 = G[(size_t)s3*64+gj];
    unsigned w4 = G[(size_t)s4*64+gj], w5 = G[(size_t)s5*64+gj];
    unsigned w6 = G[(size_t)s6*64+gj], w7 = G[(size_t)s7*64+gj];
    float v0 = edge_w(q0, adh), v1 = edge_w(q1, adh), v2 = edge_w(q2, adh), v3 = edge_w(q3, adh);
    float v4 = edge_w(q4, adh), v5 = edge_w(q5, adh), v6 = edge_w(q6, adh), v7 = edge_w(q7, adh);
    psum += (v0 + v1 + v2 + v3) + (v4 + v5 + v6 + v7);
    agg0 = fmaf(v0, bflo(w0), agg0); agg1 = fmaf(v0, bfhi(w0), agg1);
    agg0 = fmaf(v1, bflo(w1), agg0); agg1 = fmaf(v1, bfhi(w1), agg1);
    agg0 = fmaf(v2, bflo(w2), agg0); agg1 = fmaf(v2, bfhi(w2), agg1);
    agg0 = fmaf(v3, bflo(w3), agg0); agg1 = fmaf(v3, bfhi(w3), agg1);
    agg0 = fmaf(v4, bflo(w4), agg0); agg1 = fmaf(v4, bfhi(w4), agg1);
    agg0 = fmaf(v5, bflo(w5), agg0); agg1 = fmaf(v5, bfhi(w5), agg1);
    agg0 = fmaf(v6, bflo(w6), agg0); agg1 = fmaf(v6, bfhi(w6), agg1);
    agg0 = fmaf(v7, bflo(w7), agg0); agg1 = fmaf(v7, bfhi(w7), agg1);
  }
  for (; i < hi; i++) {
    int s = esrc[i];
    float q = a_src1[(size_t)s * 8 + g];
    unsigned w0 = G[(size_t)s * 64 + gj];
    float v = edge_w(q, adh);
    psum += v;
    agg0 = fmaf(v, bflo(w0), agg0); agg1 = fmaf(v, bfhi(w0), agg1);
  }
  const float inv = 1.f / (psum + 1e-16f);
  float v0 = agg0 * inv, v1 = agg1 * inv;
  {
    const float* xr = &X[(size_t)n * 128 + g * 16];
    const float* wr0 = &W1pT[(2 * j0) * 128 + g * 16];
    const float* wr1 = &W1pT[(2 * j0 + 1) * 128 + g * 16];
    #pragma unroll
    for (int c = 0; c < 16; c += 4) {
      float4 xa = *reinterpret_cast<const float4*>(xr + c);
      float4 wa = *reinterpret_cast<const float4*>(wr0 + c);
      float4 wb = *reinterpret_cast<const float4*>(wr1 + c);
      v0 += xa.x * wa.x + xa.y * wa.y + xa.z * wa.z + xa.w * wa.w;
      v1 += xa.x * wb.x + xa.y * wb.y + xa.z * wb.z + xa.w * wb.w;
    }
  }
  v0 += __shfl_xor(v0, 8); v0 += __shfl_xor(v0, 16); v0 += __shfl_xor(v0, 32);
  v1 += __shfl_xor(v1, 8); v1 += __shfl_xor(v1, 16); v1 += __shfl_xor(v1, 32);
  float o0 = v0 + b3p[2 * j0];
  float o1 = v1 + b3p[2 * j0 + 1];
  if (g == 0) reinterpret_cast<unsigned*>(H3b)[(size_t)n * 8 + j0] = cvtpk(o0, o1);
  float vs = o0 * g3_as[2 * j0] + o1 * g3_as[2 * j0 + 1];
  float vd = o0 * g3_ad[2 * j0] + o1 * g3_ad[2 * j0 + 1];
  vs += __shfl_xor(vs, 1); vs += __shfl_xor(vs, 2); vs += __shfl_xor(vs, 4);
  vd += __shfl_xor(vd, 1); vd += __shfl_xor(vd, 2); vd += __shfl_xor(vd, 4);
  if (l == 0) { a3s[n] = vs; a3d[n] = vd; }
}

// ---------------- gat3 aggregation (bf16 H3) -> d_out. Wave/node, 4 groups x 16 ch.
__global__ __launch_bounds__(256)
void agg3_kernel(const int* __restrict__ offs, const int* __restrict__ esrc,
                 const float* __restrict__ a3s, const float* __restrict__ a3d,
                 const bf16* __restrict__ H3b, const float* __restrict__ g3_b,
                 float* __restrict__ out, int N) {
  const int l = threadIdx.x & 63;
  const int n = blockIdx.x * 4 + (threadIdx.x >> 6);
  if (n >= N) return;
  const int g = l >> 4, j = l & 15;
  const float ad = a3d[n];
  const ushort* __restrict__ H = reinterpret_cast<const ushort*>(H3b);
  const int lo = offs[n], hi = offs[n + 1];
  float acc = 0.f, psum = 0.f;
  int i = lo + g;
  for (; i + 12 < hi; i += 16) {
    int s0 = esrc[i], s1 = esrc[i + 4], s2 = esrc[i + 8], s3 = esrc[i + 12];
    float q0 = a3s[s0], q1 = a3s[s1], q2 = a3s[s2], q3 = a3s[s3];
    float h0 = __uint_as_float((unsigned)H[(size_t)s0 * 16 + j] << 16);
    float h1 = __uint_as_float((unsigned)H[(size_t)s1 * 16 + j] << 16);
    float h2 = __uint_as_float((unsigned)H[(size_t)s2 * 16 + j] << 16);
    float h3v = __uint_as_float((unsigned)H[(size_t)s3 * 16 + j] << 16);
    float v0 = edge_w(q0, ad), v1 = edge_w(q1, ad);
    float v2 = edge_w(q2, ad), v3 = edge_w(q3, ad);
    psum += (v0 + v1) + (v2 + v3);
    acc = fmaf(v0, h0, acc); acc = fmaf(v1, h1, acc);
    acc = fmaf(v2, h2, acc); acc = fmaf(v3, h3v, acc);
  }
  for (; i < hi; i += 4) {
    int s = esrc[i];
    float v = edge_w(a3s[s], ad);
    psum += v;
    acc = fmaf(v, __uint_as_float((unsigned)H[(size_t)s * 16 + j] << 16), acc);
  }
  acc += __shfl_xor(acc, 16);  acc += __shfl_xor(acc, 32);
  psum += __shfl_xor(psum, 16); psum += __shfl_xor(psum, 32);
  if (l < 16) out[(size_t)n * 16 + j] = acc / (psum + 1e-16f) + g3_b[j];
}

__global__ void sentinel_kernel(float* out) { out[threadIdx.x] = -1e9f; }

extern "C" void kernel_launch(void* const* d_in, const int* in_sizes, int n_in,
                              void* d_out, int out_size, void* d_ws, size_t ws_size,
                              hipStream_t stream) {
  const float* x      = (const float*)d_in[0];
  const int*   ei     = (const int*)d_in[1];
  const float* g1_W   = (const float*)d_in[2];
  const float* g1_as  = (const float*)d_in[3];
  const float* g1_ad  = (const float*)d_in[4];
  const float* g1_b   = (const float*)d_in[5];
  const float* sk1_W  = (const float*)d_in[6];
  const float* sk1_b  = (const float*)d_in[7];
  const float* sk2_W  = (const float*)d_in[8];
  const float* sk2_b  = (const float*)d_in[9];
  const float* g3_W   = (const float*)d_in[10];
  const float* g3_as  = (const float*)d_in[11];
  const float* g3_ad  = (const float*)d_in[12];
  const float* g3_b   = (const float*)d_in[13];
  float* out = (float*)d_out;

  const int N  = in_sizes[0] / 128;
  const int E  = in_sizes[1] / 2;
  const int EP = E + N;
  const int Mt = (N + 63) / 64;
  const int Np = Mt * 64;
  const int NB = (N + 1023) / 1024;   // scan chunks

  char* w = (char*)d_ws;
  size_t off = 0;
  auto alloc = [&](size_t bytes) -> void* {
    void* p = w + off;
    off = (off + bytes + 255) & ~(size_t)255;
    return p;
  };

  // zero-init block (single memset)
  int* deg    = (int*)alloc((size_t)N * 4);
  int* cursor = (int*)alloc((size_t)N * 4);
  size_t zbytes = off;
  // rest of workspace
  int*   offs   = (int*)alloc((size_t)(N + 1) * 4);
  int*   bsum   = (int*)alloc((size_t)NB * 4);
  int*   esrc   = (int*)alloc((size_t)EP * 4);
  bf16*  xbX    = (bf16*)alloc((size_t)Np * 128 * 2);
  bf16*  WtX    = (bf16*)alloc(512 * 128 * 2);
  bf16*  W2pSa  = (bf16*)alloc(8192 * 2);
  bf16*  g1p    = (bf16*)alloc((size_t)N * 128 * 2);
  float* a_src1 = (float*)alloc((size_t)N * 8 * 4);
  float* a_dst1 = (float*)alloc((size_t)N * 8 * 4);
  bf16*  h3b    = (bf16*)alloc((size_t)N * 16 * 2);
  float* a_src3 = (float*)alloc((size_t)N * 4);
  float* a_dst3 = (float*)alloc((size_t)N * 4);
  float* W1pT   = (float*)alloc(128 * 16 * 4);
  float* W2pT   = (float*)alloc(512 * 16 * 4);
  float* b3p    = (float*)alloc(16 * 4);
  (void)n_in; (void)out_size;

  if (off > ws_size) {  // workspace too small: fail loudly but safely
    sentinel_kernel<<<1, 16, 0, stream>>>(out);
    return;
  }

  hipMemsetAsync(d_ws, 0, zbytes, stream);

  const int eb = (EP + 255) / 256;
  const int nb4 = (N + 3) / 4;
  // setup partition: [0,bX) cast_x | [bX,bWT) cast_wt | w1p | w2p | deg
  const int bX = 1024, bWT = bX + 256, bW1 = bWT + 8, bW2 = bW1 + 32;

  setup_kernel<<<bW2 + eb, 256, 0, stream>>>(
      x, ei, g1_W, sk1_W, sk2_W, g3_W,
      xbX, WtX, W1pT, W2pT, W2pSa, deg, N, Np, E, EP, bX, bWT, bW1, bW2);
  setup2_kernel<<<1, 256, 0, stream>>>(sk1_b, sk2_b, g1_b, g3_W, W2pT, b3p);

  scan1_kernel<<<NB, 256, 0, stream>>>(deg, offs, bsum, N);
  scan2_kernel<<<1, 256, 0, stream>>>(bsum, NB, offs, N);
  scan3_kernel<<<NB, 256, 0, stream>>>(offs, bsum, N);
  scatter_kernel<<<eb, 256, 0, stream>>>(ei, offs, cursor, esrc, E, EP);

  gemm_h1_kernel<<<dim3(Mt, 4), 256, 0, stream>>>(
      xbX, WtX, W2pSa, g1_as, g1_ad, g1p, a_src1, a_dst1, N);

  agg1_h3_kernel<<<nb4, 256, 0, stream>>>(offs, esrc, a_src1, a_dst1, g1p, x,
                                          W1pT, b3p, g3_as, g3_ad,
                                          h3b, a_src3, a_dst3, N);

  agg3_kernel<<<nb4, 256, 0, stream>>>(offs, esrc, a_src3, a_dst3, h3b, g3_b, out, N);
}

// Round 9
// 336.100 us; speedup vs baseline: 2.6491x; 1.0197x over previous
//
#include <hip/hip_runtime.h>
#include <hip/hip_bf16.h>

#define NEG_SLOPE 0.2f
using bf16 = __hip_bfloat16;

typedef __attribute__((ext_vector_type(8))) short short8;   // 8 bf16 (4 VGPRs)
typedef __attribute__((ext_vector_type(4))) float f32x4;
#define MFMA16(a, b, c) __builtin_amdgcn_mfma_f32_16x16x32_bf16(a, b, c, 0, 0, 0)

__device__ __forceinline__ float bflo(unsigned u) { return __uint_as_float(u << 16); }
__device__ __forceinline__ float bfhi(unsigned u) { return __uint_as_float(u & 0xffff0000u); }

__device__ __forceinline__ unsigned cvtpk(float lo, float hi) {
  unsigned r;
  asm volatile("v_cvt_pk_bf16_f32 %0, %1, %2" : "=v"(r) : "v"(lo), "v"(hi));
  return r;
}

__device__ __forceinline__ float edge_w(float q, float adh) {
  float t = q + adh;
  t = (t > 0.f) ? t : NEG_SLOPE * t;
  return __expf(t);
}

// MFMA-fragment packed offset: (tile, kc, lk, r, e) for 16-row tiles, K=128
__device__ __forceinline__ size_t frag_off(int row, int k) {
  return (size_t)(row >> 4) * 2048 + (k >> 5) * 512 + ((k >> 3) & 3) * 128 +
         (row & 15) * 8 + (k & 7);
}

// ---------------- fused setup: cast_x->xbX, cast_wt->WtX, w1p, w2p(+W2pSa frags), deg
__global__ __launch_bounds__(256)
void setup_kernel(const float* __restrict__ x, const int* __restrict__ ei,
                  const float* __restrict__ g1_W,
                  const float* __restrict__ sk1_W,
                  const float* __restrict__ sk2_W,
                  const float* __restrict__ g3_W,
                  bf16* __restrict__ xbX, bf16* __restrict__ WtX,
                  float* __restrict__ W1pT, float* __restrict__ W2pT,
                  bf16* __restrict__ W2pSa, int* __restrict__ deg,
                  int N, int Np, int E, int EP,
                  int bX, int bWT, int bW1, int bW2) {
  const int b = blockIdx.x;
  const int t = threadIdx.x;
  if (b < bX) {                       // x -> xbX (packed MFMA frag layout, zero pad)
    const int total4 = Np * 32;
    const int stride = bX * 256;
    for (int i = b * 256 + t; i < total4; i += stride) {
      int row = i >> 5, kq = (i & 31) * 4;
      float4 v = make_float4(0.f, 0.f, 0.f, 0.f);
      if (row < N) v = reinterpret_cast<const float4*>(x)[i];
      union { bf16 bv[4]; ushort4 u; } pk;
      pk.bv[0] = __float2bfloat16(v.x); pk.bv[1] = __float2bfloat16(v.y);
      pk.bv[2] = __float2bfloat16(v.z); pk.bv[3] = __float2bfloat16(v.w);
      *reinterpret_cast<ushort4*>(&xbX[frag_off(row, kq)]) = pk.u;
    }
  } else if (b < bWT) {               // g1_W -> WtX (packed MFMA frag layout)
    int i = (b - bX) * 256 + t;       // 65536 exactly
    int k = i >> 9, c = i & 511;
    WtX[frag_off(c, k)] = __float2bfloat16(g1_W[k * 512 + c]);
  } else if (b < bW1) {               // W1pT[16][128]
    int i = (b - bWT) * 256 + t;      // 2048
    int j = i >> 7, k = i & 127;
    float acc = 0.f;
    for (int m = 0; m < 512; m++) acc += sk1_W[k * 512 + m] * g3_W[m * 16 + j];
    W1pT[i] = acc;
  } else if (b < bW2) {               // W2pT[16][512] + packed A-frags W2pSa
    int i = (b - bW1) * 256 + t;      // 8192
    int j = i >> 9, c = i & 511;
    float acc = 0.f;
    for (int m = 0; m < 512; m++) acc += sk2_W[c * 512 + m] * g3_W[(512 + m) * 16 + j];
    W2pT[i] = acc;
    int h = c >> 6, cc = c & 63, kk = cc >> 5, lk = (cc >> 3) & 3, e = cc & 7;
    W2pSa[((size_t)(h * 2 + kk) * 64 + (j + 16 * lk)) * 8 + e] = __float2bfloat16(acc);
  } else {                            // degree histogram
    int e = (b - bW2) * 256 + t;
    if (e < EP) {
      int d = (e < E) ? ei[E + e] : (e - E);
      atomicAdd(&deg[d], 1);
    }
  }
}

// ---------------- scan1 (per-chunk excl scan) + setup2 (b3p) fused by block range
__global__ __launch_bounds__(256)
void scan1_setup2_kernel(const int* __restrict__ deg, int* __restrict__ offs,
                         int* __restrict__ bsum, int n, int NB,
                         const float* __restrict__ sk1_b, const float* __restrict__ sk2_b,
                         const float* __restrict__ g1_b, const float* __restrict__ g3_W,
                         const float* __restrict__ W2pT, float* __restrict__ b3p) {
  const int b = blockIdx.x, t = threadIdx.x;
  if (b == NB) {                      // setup2
    __shared__ float red[16][16];
    int j = t & 15, seg = t >> 4;
    float acc = 0.f;
    for (int m = seg * 32; m < seg * 32 + 32; m++)
      acc += sk1_b[m] * g3_W[m * 16 + j] + sk2_b[m] * g3_W[(512 + m) * 16 + j];
    for (int c = seg * 32; c < seg * 32 + 32; c++)
      acc += g1_b[c] * W2pT[j * 512 + c];
    red[seg][j] = acc;
    __syncthreads();
    if (t < 16) {
      float s = 0.f;
      for (int k = 0; k < 16; k++) s += red[k][t];
      b3p[t] = s;
    }
    return;
  }
  __shared__ int ts[256];
  const int base = b * 1024 + t * 4;
  int4 v = make_int4(0, 0, 0, 0);
  if (base + 3 < n) v = *reinterpret_cast<const int4*>(&deg[base]);
  else {
    if (base + 0 < n) v.x = deg[base + 0];
    if (base + 1 < n) v.y = deg[base + 1];
    if (base + 2 < n) v.z = deg[base + 2];
  }
  ts[t] = v.x + v.y + v.z + v.w;
  __syncthreads();
  for (int st = 1; st < 256; st <<= 1) {
    int u = (t >= st) ? ts[t - st] : 0;
    __syncthreads();
    ts[t] += u;
    __syncthreads();
  }
  int excl = (t == 0) ? 0 : ts[t - 1];
  int4 o;
  o.x = excl;
  o.y = o.x + v.x;
  o.z = o.y + v.y;
  o.w = o.z + v.z;
  if (base + 3 < n) *reinterpret_cast<int4*>(&offs[base]) = o;
  else {
    if (base + 0 < n) offs[base + 0] = o.x;
    if (base + 1 < n) offs[base + 1] = o.y;
    if (base + 2 < n) offs[base + 2] = o.z;
  }
  if (t == 255) bsum[b] = ts[255];
}

// ---------------- scan3: each block self-computes prefix of bsum[0..b) and adds
__global__ __launch_bounds__(256)
void scan3_kernel(int* __restrict__ offs, const int* __restrict__ bsum, int n, int NB) {
  __shared__ float dummy;
  __shared__ int wred[4];
  const int b = blockIdx.x, t = threadIdx.x;
  (void)dummy;
  int part = (t < b) ? bsum[t] : 0;            // NB <= 256 assumed
  #pragma unroll
  for (int m = 1; m < 64; m <<= 1) part += __shfl_xor(part, m);
  if ((t & 63) == 0) wred[t >> 6] = part;
  __syncthreads();
  const int add = wred[0] + wred[1] + wred[2] + wred[3];
  if (b == NB - 1 && t == 0) offs[n] = add + bsum[b];
  if (add == 0) return;
  const int base = b * 1024 + t * 4;
  if (base + 3 < n) {
    int4 o = *reinterpret_cast<const int4*>(&offs[base]);
    o.x += add; o.y += add; o.z += add; o.w += add;
    *reinterpret_cast<int4*>(&offs[base]) = o;
  } else {
    if (base + 0 < n) offs[base + 0] += add;
    if (base + 1 < n) offs[base + 1] += add;
    if (base + 2 < n) offs[base + 2] += add;
  }
}

// ---------------- FUSED: MFMA GEMM (+att dots +g1p projection)  ||  CSR scatter.
// Blocks [0, Mt*4) do gemm; blocks [Mt*4, Mt*4+eb) do scatter — independent work
// running concurrently in one launch.
__global__ __launch_bounds__(256)
void gemm_scatter_kernel(const bf16* __restrict__ xbX, const bf16* __restrict__ WtX,
                         const bf16* __restrict__ W2pSa,
                         const float* __restrict__ att_s, const float* __restrict__ att_d,
                         bf16* __restrict__ g1p, float* __restrict__ a_src,
                         float* __restrict__ a_dst,
                         const int* __restrict__ ei, const int* __restrict__ offs,
                         int* __restrict__ cursor, int* __restrict__ esrc,
                         int M, int Mt, int E, int EP) {
  const int gb = Mt * 4;
  if (blockIdx.x >= gb) {             // ---- scatter part
    int e = (blockIdx.x - gb) * 256 + threadIdx.x;
    if (e < EP) {
      int s = (e < E) ? ei[e] : (e - E);
      int d = (e < E) ? ei[E + e] : (e - E);
      int pos = offs[d] + atomicAdd(&cursor[d], 1);
      esrc[pos] = s;
    }
    return;
  }
  // ---- gemm part
  const int bx = blockIdx.x % Mt;
  const int by = blockIdx.x / Mt;
  const int t = threadIdx.x;
  const int w = t >> 6, l = t & 63;
  const int wm = w & 1, wn = w >> 1;
  const int m0 = bx * 64 + wm * 32;
  const int n0 = by * 128 + wn * 64;
  const int head = n0 >> 6;
  const int lr = l & 15, lk = l >> 4;
  const bf16* aBase = xbX + (size_t)(m0 >> 4) * 2048 + l * 8;
  const bf16* bBase = WtX + (size_t)(n0 >> 4) * 2048 + l * 8;
  f32x4 accT[4][2] = {};   // accT[ni][mi]: lane holds h1[xrow=mi*16+lr, wcol=ni*16+lk*4+r]
  #pragma unroll
  for (int kc = 0; kc < 4; kc++) {
    short8 av0 = *reinterpret_cast<const short8*>(aBase + kc * 512);
    short8 av1 = *reinterpret_cast<const short8*>(aBase + 2048 + kc * 512);
    short8 bv0 = *reinterpret_cast<const short8*>(bBase + 0 * 2048 + kc * 512);
    short8 bv1 = *reinterpret_cast<const short8*>(bBase + 1 * 2048 + kc * 512);
    short8 bv2 = *reinterpret_cast<const short8*>(bBase + 2 * 2048 + kc * 512);
    short8 bv3 = *reinterpret_cast<const short8*>(bBase + 3 * 2048 + kc * 512);
    accT[0][0] = MFMA16(bv0, av0, accT[0][0]);
    accT[1][0] = MFMA16(bv1, av0, accT[1][0]);
    accT[2][0] = MFMA16(bv2, av0, accT[2][0]);
    accT[3][0] = MFMA16(bv3, av0, accT[3][0]);
    accT[0][1] = MFMA16(bv0, av1, accT[0][1]);
    accT[1][1] = MFMA16(bv1, av1, accT[1][1]);
    accT[2][1] = MFMA16(bv2, av1, accT[2][1]);
    accT[3][1] = MFMA16(bv3, av1, accT[3][1]);
  }
  #pragma unroll
  for (int mi = 0; mi < 2; mi++) {
    float vs = 0.f, vd = 0.f;
    #pragma unroll
    for (int ni = 0; ni < 4; ni++) {
      float4 as4 = *reinterpret_cast<const float4*>(&att_s[head * 64 + ni * 16 + lk * 4]);
      float4 ad4 = *reinterpret_cast<const float4*>(&att_d[head * 64 + ni * 16 + lk * 4]);
      vs += accT[ni][mi][0] * as4.x + accT[ni][mi][1] * as4.y +
            accT[ni][mi][2] * as4.z + accT[ni][mi][3] * as4.w;
      vd += accT[ni][mi][0] * ad4.x + accT[ni][mi][1] * ad4.y +
            accT[ni][mi][2] * ad4.z + accT[ni][mi][3] * ad4.w;
    }
    vs += __shfl_xor(vs, 16); vs += __shfl_xor(vs, 32);
    vd += __shfl_xor(vd, 16); vd += __shfl_xor(vd, 32);
    int row = m0 + mi * 16 + lr;
    if (lk == 0 && row < M) {
      a_src[(size_t)row * 8 + head] = vs;
      a_dst[(size_t)row * 8 + head] = vd;
    }
  }
  unsigned pk[4][2][2];
  #pragma unroll
  for (int ni = 0; ni < 4; ni++)
    #pragma unroll
    for (int mi = 0; mi < 2; mi++) {
      pk[ni][mi][0] = cvtpk(accT[ni][mi][0], accT[ni][mi][1]);
      pk[ni][mi][1] = cvtpk(accT[ni][mi][2], accT[ni][mi][3]);
    }
  f32x4 d3[2] = {};
  #pragma unroll
  for (int kk = 0; kk < 2; kk++) {
    short8 aw2 = *reinterpret_cast<const short8*>(&W2pSa[((size_t)(head * 2 + kk) * 64 + l) * 8]);
    #pragma unroll
    for (int mi = 0; mi < 2; mi++) {
      union { unsigned u[4]; short8 s8; } bf;
      #pragma unroll
      for (int v = 0; v < 4; v++) {
        int src = lr + 16 * ((lk & 1) * 2 + (v >> 1));
        unsigned t0 = __shfl(pk[2 * kk][mi][v & 1], src);
        unsigned t1 = __shfl(pk[2 * kk + 1][mi][v & 1], src);
        bf.u[v] = (lk & 2) ? t1 : t0;
      }
      d3[mi] = MFMA16(aw2, bf.s8, d3[mi]);
    }
  }
  #pragma unroll
  for (int mi = 0; mi < 2; mi++) {
    int row = m0 + mi * 16 + lr;           // d3[mi]: col=lr=xrow, j=lk*4+reg
    if (row < M) {
      uint2 st;
      st.x = cvtpk(d3[mi][0], d3[mi][1]);
      st.y = cvtpk(d3[mi][2], d3[mi][3]);
      *reinterpret_cast<uint2*>(&g1p[(size_t)row * 128 + head * 16 + lk * 4]) = st;
    }
  }
}

// ---------------- FUSED: gat1 softmax-agg over PROJECTED g1p + x@W1p + att3. Unroll 16.
__global__ __launch_bounds__(256)
void agg1_h3_kernel(const int* __restrict__ offs, const int* __restrict__ esrc,
                    const float* __restrict__ a_src1, const float* __restrict__ a_dst1,
                    const bf16* __restrict__ g1p,
                    const float* __restrict__ X,
                    const float* __restrict__ W1pT, const float* __restrict__ b3p,
                    const float* __restrict__ g3_as, const float* __restrict__ g3_ad,
                    bf16* __restrict__ H3b, float* __restrict__ a3s, float* __restrict__ a3d,
                    int N) {
  const int l = threadIdx.x & 63;
  const int n = blockIdx.x * 4 + (threadIdx.x >> 6);
  if (n >= N) return;
  const int g = l >> 3, j0 = l & 7;
  const float adh = a_dst1[n * 8 + g];
  const unsigned* __restrict__ G = reinterpret_cast<const unsigned*>(g1p);  // 64 u32/row
  const int lo = offs[n], hi = offs[n + 1];
  const int gj = g * 8 + j0;
  float agg0 = 0.f, agg1 = 0.f, psum = 0.f;
  int i = lo;
  for (; i + 16 <= hi; i += 16) {        // 16 rows in flight
    int ss[16]; float qq[16]; unsigned ww[16];
    #pragma unroll
    for (int k = 0; k < 16; k++) ss[k] = esrc[i + k];
    #pragma unroll
    for (int k = 0; k < 16; k++) ww[k] = G[(size_t)ss[k] * 64 + gj];
    #pragma unroll
    for (int k = 0; k < 16; k++) qq[k] = a_src1[(size_t)ss[k] * 8 + g];
    #pragma unroll
    for (int k = 0; k < 16; k++) {
      float v = edge_w(qq[k], adh);
      psum += v;
      agg0 = fmaf(v, bflo(ww[k]), agg0);
      agg1 = fmaf(v, bfhi(ww[k]), agg1);
    }
  }
  if (i + 8 <= hi) {
    int ss[8]; float qq[8]; unsigned ww[8];
    #pragma unroll
    for (int k = 0; k < 8; k++) ss[k] = esrc[i + k];
    #pragma unroll
    for (int k = 0; k < 8; k++) ww[k] = G[(size_t)ss[k] * 64 + gj];
    #pragma unroll
    for (int k = 0; k < 8; k++) qq[k] = a_src1[(size_t)ss[k] * 8 + g];
    #pragma unroll
    for (int k = 0; k < 8; k++) {
      float v = edge_w(qq[k], adh);
      psum += v;
      agg0 = fmaf(v, bflo(ww[k]), agg0);
      agg1 = fmaf(v, bfhi(ww[k]), agg1);
    }
    i += 8;
  }
  for (; i < hi; i++) {
    int s = esrc[i];
    float q = a_src1[(size_t)s * 8 + g];
    unsigned w0 = G[(size_t)s * 64 + gj];
    float v = edge_w(q, adh);
    psum += v;
    agg0 = fmaf(v, bflo(w0), agg0); agg1 = fmaf(v, bfhi(w0), agg1);
  }
  const float inv = 1.f / (psum + 1e-16f);
  float v0 = agg0 * inv, v1 = agg1 * inv;
  {
    const float* xr = &X[(size_t)n * 128 + g * 16];
    const float* wr0 = &W1pT[(2 * j0) * 128 + g * 16];
    const float* wr1 = &W1pT[(2 * j0 + 1) * 128 + g * 16];
    #pragma unroll
    for (int c = 0; c < 16; c += 4) {
      float4 xa = *reinterpret_cast<const float4*>(xr + c);
      float4 wa = *reinterpret_cast<const float4*>(wr0 + c);
      float4 wb = *reinterpret_cast<const float4*>(wr1 + c);
      v0 += xa.x * wa.x + xa.y * wa.y + xa.z * wa.z + xa.w * wa.w;
      v1 += xa.x * wb.x + xa.y * wb.y + xa.z * wb.z + xa.w * wb.w;
    }
  }
  v0 += __shfl_xor(v0, 8); v0 += __shfl_xor(v0, 16); v0 += __shfl_xor(v0, 32);
  v1 += __shfl_xor(v1, 8); v1 += __shfl_xor(v1, 16); v1 += __shfl_xor(v1, 32);
  float o0 = v0 + b3p[2 * j0];
  float o1 = v1 + b3p[2 * j0 + 1];
  if (g == 0) reinterpret_cast<unsigned*>(H3b)[(size_t)n * 8 + j0] = cvtpk(o0, o1);
  float vs = o0 * g3_as[2 * j0] + o1 * g3_as[2 * j0 + 1];
  float vd = o0 * g3_ad[2 * j0] + o1 * g3_ad[2 * j0 + 1];
  vs += __shfl_xor(vs, 1); vs += __shfl_xor(vs, 2); vs += __shfl_xor(vs, 4);
  vd += __shfl_xor(vd, 1); vd += __shfl_xor(vd, 2); vd += __shfl_xor(vd, 4);
  if (l == 0) { a3s[n] = vs; a3d[n] = vd; }
}

// ---------------- gat3 aggregation (bf16 H3) -> d_out. Wave/node, 4 groups x 16 ch.
__global__ __launch_bounds__(256)
void agg3_kernel(const int* __restrict__ offs, const int* __restrict__ esrc,
                 const float* __restrict__ a3s, const float* __restrict__ a3d,
                 const bf16* __restrict__ H3b, const float* __restrict__ g3_b,
                 float* __restrict__ out, int N) {
  const int l = threadIdx.x & 63;
  const int n = blockIdx.x * 4 + (threadIdx.x >> 6);
  if (n >= N) return;
  const int g = l >> 4, j = l & 15;
  const float ad = a3d[n];
  const ushort* __restrict__ H = reinterpret_cast<const ushort*>(H3b);
  const int lo = offs[n], hi = offs[n + 1];
  float acc = 0.f, psum = 0.f;
  int i = lo + g;
  for (; i + 12 < hi; i += 16) {
    int s0 = esrc[i], s1 = esrc[i + 4], s2 = esrc[i + 8], s3 = esrc[i + 12];
    float q0 = a3s[s0], q1 = a3s[s1], q2 = a3s[s2], q3 = a3s[s3];
    float h0 = __uint_as_float((unsigned)H[(size_t)s0 * 16 + j] << 16);
    float h1 = __uint_as_float((unsigned)H[(size_t)s1 * 16 + j] << 16);
    float h2 = __uint_as_float((unsigned)H[(size_t)s2 * 16 + j] << 16);
    float h3v = __uint_as_float((unsigned)H[(size_t)s3 * 16 + j] << 16);
    float v0 = edge_w(q0, ad), v1 = edge_w(q1, ad);
    float v2 = edge_w(q2, ad), v3 = edge_w(q3, ad);
    psum += (v0 + v1) + (v2 + v3);
    acc = fmaf(v0, h0, acc); acc = fmaf(v1, h1, acc);
    acc = fmaf(v2, h2, acc); acc = fmaf(v3, h3v, acc);
  }
  for (; i < hi; i += 4) {
    int s = esrc[i];
    float v = edge_w(a3s[s], ad);
    psum += v;
    acc = fmaf(v, __uint_as_float((unsigned)H[(size_t)s * 16 + j] << 16), acc);
  }
  acc += __shfl_xor(acc, 16);  acc += __shfl_xor(acc, 32);
  psum += __shfl_xor(psum, 16); psum += __shfl_xor(psum, 32);
  if (l < 16) out[(size_t)n * 16 + j] = acc / (psum + 1e-16f) + g3_b[j];
}

__global__ void sentinel_kernel(float* out) { out[threadIdx.x] = -1e9f; }

extern "C" void kernel_launch(void* const* d_in, const int* in_sizes, int n_in,
                              void* d_out, int out_size, void* d_ws, size_t ws_size,
                              hipStream_t stream) {
  const float* x      = (const float*)d_in[0];
  const int*   ei     = (const int*)d_in[1];
  const float* g1_W   = (const float*)d_in[2];
  const float* g1_as  = (const float*)d_in[3];
  const float* g1_ad  = (const float*)d_in[4];
  const float* g1_b   = (const float*)d_in[5];
  const float* sk1_W  = (const float*)d_in[6];
  const float* sk1_b  = (const float*)d_in[7];
  const float* sk2_W  = (const float*)d_in[8];
  const float* sk2_b  = (const float*)d_in[9];
  const float* g3_W   = (const float*)d_in[10];
  const float* g3_as  = (const float*)d_in[11];
  const float* g3_ad  = (const float*)d_in[12];
  const float* g3_b   = (const float*)d_in[13];
  float* out = (float*)d_out;

  const int N  = in_sizes[0] / 128;
  const int E  = in_sizes[1] / 2;
  const int EP = E + N;
  const int Mt = (N + 63) / 64;
  const int Np = Mt * 64;
  const int NB = (N + 1023) / 1024;   // scan chunks (<= 256 assumed; 98 here)

  char* w = (char*)d_ws;
  size_t off = 0;
  auto alloc = [&](size_t bytes) -> void* {
    void* p = w + off;
    off = (off + bytes + 255) & ~(size_t)255;
    return p;
  };

  // zero-init block (single memset)
  int* deg    = (int*)alloc((size_t)N * 4);
  int* cursor = (int*)alloc((size_t)N * 4);
  size_t zbytes = off;
  // rest of workspace
  int*   offs   = (int*)alloc((size_t)(N + 1) * 4);
  int*   bsum   = (int*)alloc((size_t)NB * 4);
  int*   esrc   = (int*)alloc((size_t)EP * 4);
  bf16*  xbX    = (bf16*)alloc((size_t)Np * 128 * 2);
  bf16*  WtX    = (bf16*)alloc(512 * 128 * 2);
  bf16*  W2pSa  = (bf16*)alloc(8192 * 2);
  bf16*  g1p    = (bf16*)alloc((size_t)N * 128 * 2);
  float* a_src1 = (float*)alloc((size_t)N * 8 * 4);
  float* a_dst1 = (float*)alloc((size_t)N * 8 * 4);
  bf16*  h3b    = (bf16*)alloc((size_t)N * 16 * 2);
  float* a_src3 = (float*)alloc((size_t)N * 4);
  float* a_dst3 = (float*)alloc((size_t)N * 4);
  float* W1pT   = (float*)alloc(128 * 16 * 4);
  float* W2pT   = (float*)alloc(512 * 16 * 4);
  float* b3p    = (float*)alloc(16 * 4);
  (void)n_in; (void)out_size;

  if (off > ws_size) {  // workspace too small: fail loudly but safely
    sentinel_kernel<<<1, 16, 0, stream>>>(out);
    return;
  }

  hipMemsetAsync(d_ws, 0, zbytes, stream);

  const int eb = (EP + 255) / 256;
  const int nb4 = (N + 3) / 4;
  // setup partition: [0,bX) cast_x | [bX,bWT) cast_wt | w1p | w2p | deg
  const int bX = 1024, bWT = bX + 256, bW1 = bWT + 8, bW2 = bW1 + 32;

  setup_kernel<<<bW2 + eb, 256, 0, stream>>>(
      x, ei, g1_W, sk1_W, sk2_W, g3_W,
      xbX, WtX, W1pT, W2pT, W2pSa, deg, N, Np, E, EP, bX, bWT, bW1, bW2);

  scan1_setup2_kernel<<<NB + 1, 256, 0, stream>>>(
      deg, offs, bsum, N, NB, sk1_b, sk2_b, g1_b, g3_W, W2pT, b3p);
  scan3_kernel<<<NB, 256, 0, stream>>>(offs, bsum, N, NB);

  gemm_scatter_kernel<<<Mt * 4 + eb, 256, 0, stream>>>(
      xbX, WtX, W2pSa, g1_as, g1_ad, g1p, a_src1, a_dst1,
      ei, offs, cursor, esrc, N, Mt, E, EP);

  agg1_h3_kernel<<<nb4, 256, 0, stream>>>(offs, esrc, a_src1, a_dst1, g1p, x,
                                          W1pT, b3p, g3_as, g3_ad,
                                          h3b, a_src3, a_dst3, N);

  agg3_kernel<<<nb4, 256, 0, stream>>>(offs, esrc, a_src3, a_dst3, h3b, g3_b, out, N);
}

// Round 10
// 335.732 us; speedup vs baseline: 2.6520x; 1.0011x over previous
//
#include <hip/hip_runtime.h>
#include <hip/hip_bf16.h>

#define NEG_SLOPE 0.2f
using bf16 = __hip_bfloat16;

typedef __attribute__((ext_vector_type(8))) short short8;   // 8 bf16 (4 VGPRs)
typedef __attribute__((ext_vector_type(4))) float f32x4;
#define MFMA16(a, b, c) __builtin_amdgcn_mfma_f32_16x16x32_bf16(a, b, c, 0, 0, 0)

__device__ __forceinline__ float bflo(unsigned u) { return __uint_as_float(u << 16); }
__device__ __forceinline__ float bfhi(unsigned u) { return __uint_as_float(u & 0xffff0000u); }

__device__ __forceinline__ unsigned cvtpk(float lo, float hi) {
  unsigned r;
  asm volatile("v_cvt_pk_bf16_f32 %0, %1, %2" : "=v"(r) : "v"(lo), "v"(hi));
  return r;
}

__device__ __forceinline__ float edge_w(float q, float adh) {
  float t = q + adh;
  t = (t > 0.f) ? t : NEG_SLOPE * t;
  return __expf(t);
}

// MFMA-fragment packed offset: (tile, kc, lk, r, e) for 16-row tiles, K=128
__device__ __forceinline__ size_t frag_off(int row, int k) {
  return (size_t)(row >> 4) * 2048 + (k >> 5) * 512 + ((k >> 3) & 3) * 128 +
         (row & 15) * 8 + (k & 7);
}

// ---------------- deg histogram (first launch; scan1 can then overlap the casts)
__global__ __launch_bounds__(256)
void deg_kernel(const int* __restrict__ ei, int* __restrict__ deg, int E, int EP) {
  int e = blockIdx.x * 256 + threadIdx.x;
  if (e >= EP) return;
  int d = (e < E) ? ei[E + e] : (e - E);
  atomicAdd(&deg[d], 1);
}

// ---------------- fused mid: scan1 | cast_x | cast_wt | w1p | w2p (block-partitioned)
__global__ __launch_bounds__(256)
void mid_kernel(const int* __restrict__ deg, int* __restrict__ offs, int* __restrict__ bsum,
                const float* __restrict__ x, const float* __restrict__ g1_W,
                const float* __restrict__ sk1_W, const float* __restrict__ sk2_W,
                const float* __restrict__ g3_W,
                bf16* __restrict__ xbX, bf16* __restrict__ WtX,
                float* __restrict__ W1pT, float* __restrict__ W2pT,
                bf16* __restrict__ W2pSa,
                int N, int Np, int NB, int b1, int b2, int b3, int b4) {
  const int b = blockIdx.x;
  const int t = threadIdx.x;
  if (b < NB) {                        // ---- scan1: per-1024-chunk exclusive scan
    __shared__ int ts[256];
    const int base = b * 1024 + t * 4;
    int4 v = make_int4(0, 0, 0, 0);
    if (base + 3 < N) v = *reinterpret_cast<const int4*>(&deg[base]);
    else {
      if (base + 0 < N) v.x = deg[base + 0];
      if (base + 1 < N) v.y = deg[base + 1];
      if (base + 2 < N) v.z = deg[base + 2];
    }
    ts[t] = v.x + v.y + v.z + v.w;
    __syncthreads();
    for (int st = 1; st < 256; st <<= 1) {
      int u = (t >= st) ? ts[t - st] : 0;
      __syncthreads();
      ts[t] += u;
      __syncthreads();
    }
    int excl = (t == 0) ? 0 : ts[t - 1];
    int4 o;
    o.x = excl; o.y = o.x + v.x; o.z = o.y + v.y; o.w = o.z + v.z;
    if (base + 3 < N) *reinterpret_cast<int4*>(&offs[base]) = o;
    else {
      if (base + 0 < N) offs[base + 0] = o.x;
      if (base + 1 < N) offs[base + 1] = o.y;
      if (base + 2 < N) offs[base + 2] = o.z;
    }
    if (t == 255) bsum[b] = ts[255];
  } else if (b < b1) {                 // ---- cast_x -> xbX (packed frag, zero-pad)
    const int total4 = Np * 32;
    const int stride = (b1 - NB) * 256;
    for (int i = (b - NB) * 256 + t; i < total4; i += stride) {
      int row = i >> 5, kq = (i & 31) * 4;
      float4 v = make_float4(0.f, 0.f, 0.f, 0.f);
      if (row < N) v = reinterpret_cast<const float4*>(x)[i];
      union { bf16 bv[4]; ushort4 u; } pk;
      pk.bv[0] = __float2bfloat16(v.x); pk.bv[1] = __float2bfloat16(v.y);
      pk.bv[2] = __float2bfloat16(v.z); pk.bv[3] = __float2bfloat16(v.w);
      *reinterpret_cast<ushort4*>(&xbX[frag_off(row, kq)]) = pk.u;
    }
  } else if (b < b2) {                 // ---- cast_wt -> WtX (packed frag)
    int i = (b - b1) * 256 + t;        // 65536 exactly
    int k = i >> 9, c = i & 511;
    WtX[frag_off(c, k)] = __float2bfloat16(g1_W[k * 512 + c]);
  } else if (b < b3) {                 // ---- w1p: 2048 outputs x 8 thr
    int i = (b - b2) * 256 + t;        // < 16384
    int o = i >> 3, seg = i & 7;
    int j = o >> 7, k = o & 127;
    float acc = 0.f;
    for (int m = seg * 64; m < seg * 64 + 64; m++)
      acc += sk1_W[k * 512 + m] * g3_W[m * 16 + j];
    acc += __shfl_xor(acc, 1); acc += __shfl_xor(acc, 2); acc += __shfl_xor(acc, 4);
    if (seg == 0) W1pT[o] = acc;
  } else if (b < b4) {                 // ---- w2p: 8192 outputs x 8 thr (+W2pSa frags)
    int i = (b - b3) * 256 + t;        // < 65536
    int o = i >> 3, seg = i & 7;
    int j = o >> 9, c = o & 511;
    float acc = 0.f;
    for (int m = seg * 64; m < seg * 64 + 64; m++)
      acc += sk2_W[c * 512 + m] * g3_W[(512 + m) * 16 + j];
    acc += __shfl_xor(acc, 1); acc += __shfl_xor(acc, 2); acc += __shfl_xor(acc, 4);
    if (seg == 0) {
      W2pT[o] = acc;
      int h = c >> 6, cc = c & 63, kk = cc >> 5, lk = (cc >> 3) & 3, e = cc & 7;
      W2pSa[((size_t)(h * 2 + kk) * 64 + (j + 16 * lk)) * 8 + e] = __float2bfloat16(acc);
    }
  }
}

// ---------------- scan3 (self-computed bsum prefix) | setup2 (b3p), block-partitioned
__global__ __launch_bounds__(256)
void scan3_setup2_kernel(int* __restrict__ offs, const int* __restrict__ bsum, int n, int NB,
                         const float* __restrict__ sk1_b, const float* __restrict__ sk2_b,
                         const float* __restrict__ g1_b, const float* __restrict__ g3_W,
                         const float* __restrict__ W2pT, float* __restrict__ b3p) {
  const int b = blockIdx.x, t = threadIdx.x;
  if (b == NB) {                      // setup2
    __shared__ float red[16][16];
    int j = t & 15, seg = t >> 4;
    float acc = 0.f;
    for (int m = seg * 32; m < seg * 32 + 32; m++)
      acc += sk1_b[m] * g3_W[m * 16 + j] + sk2_b[m] * g3_W[(512 + m) * 16 + j];
    for (int c = seg * 32; c < seg * 32 + 32; c++)
      acc += g1_b[c] * W2pT[j * 512 + c];
    red[seg][j] = acc;
    __syncthreads();
    if (t < 16) {
      float s = 0.f;
      for (int k = 0; k < 16; k++) s += red[k][t];
      b3p[t] = s;
    }
    return;
  }
  __shared__ int wred[4];
  int part = (t < b) ? bsum[t] : 0;            // NB <= 256 assumed
  #pragma unroll
  for (int m = 1; m < 64; m <<= 1) part += __shfl_xor(part, m);
  if ((t & 63) == 0) wred[t >> 6] = part;
  __syncthreads();
  const int add = wred[0] + wred[1] + wred[2] + wred[3];
  if (b == NB - 1 && t == 0) offs[n] = add + bsum[b];
  if (add == 0) return;
  const int base = b * 1024 + t * 4;
  if (base + 3 < n) {
    int4 o = *reinterpret_cast<const int4*>(&offs[base]);
    o.x += add; o.y += add; o.z += add; o.w += add;
    *reinterpret_cast<int4*>(&offs[base]) = o;
  } else {
    if (base + 0 < n) offs[base + 0] += add;
    if (base + 1 < n) offs[base + 1] += add;
    if (base + 2 < n) offs[base + 2] += add;
  }
}

// ---------------- FUSED: CSR scatter (blocks first)  ||  MFMA GEMM (+att +g1p proj)
__global__ __launch_bounds__(256)
void gemm_scatter_kernel(const bf16* __restrict__ xbX, const bf16* __restrict__ WtX,
                         const bf16* __restrict__ W2pSa,
                         const float* __restrict__ att_s, const float* __restrict__ att_d,
                         bf16* __restrict__ g1p, float* __restrict__ a_src,
                         float* __restrict__ a_dst,
                         const int* __restrict__ ei, const int* __restrict__ offs,
                         int* __restrict__ cursor, int* __restrict__ esrc,
                         int M, int Mt, int E, int EP, int eb) {
  if (blockIdx.x < eb) {              // ---- scatter part (scheduled first)
    int e = blockIdx.x * 256 + threadIdx.x;
    if (e < EP) {
      int s = (e < E) ? ei[e] : (e - E);
      int d = (e < E) ? ei[E + e] : (e - E);
      int pos = offs[d] + atomicAdd(&cursor[d], 1);
      esrc[pos] = s;
    }
    return;
  }
  // ---- gemm part
  const int gb = blockIdx.x - eb;
  const int bx = gb % Mt;
  const int by = gb / Mt;
  const int t = threadIdx.x;
  const int w = t >> 6, l = t & 63;
  const int wm = w & 1, wn = w >> 1;
  const int m0 = bx * 64 + wm * 32;
  const int n0 = by * 128 + wn * 64;
  const int head = n0 >> 6;
  const int lr = l & 15, lk = l >> 4;
  const bf16* aBase = xbX + (size_t)(m0 >> 4) * 2048 + l * 8;
  const bf16* bBase = WtX + (size_t)(n0 >> 4) * 2048 + l * 8;
  f32x4 accT[4][2] = {};   // accT[ni][mi]: lane holds h1[xrow=mi*16+lr, wcol=ni*16+lk*4+r]
  #pragma unroll
  for (int kc = 0; kc < 4; kc++) {
    short8 av0 = *reinterpret_cast<const short8*>(aBase + kc * 512);
    short8 av1 = *reinterpret_cast<const short8*>(aBase + 2048 + kc * 512);
    short8 bv0 = *reinterpret_cast<const short8*>(bBase + 0 * 2048 + kc * 512);
    short8 bv1 = *reinterpret_cast<const short8*>(bBase + 1 * 2048 + kc * 512);
    short8 bv2 = *reinterpret_cast<const short8*>(bBase + 2 * 2048 + kc * 512);
    short8 bv3 = *reinterpret_cast<const short8*>(bBase + 3 * 2048 + kc * 512);
    accT[0][0] = MFMA16(bv0, av0, accT[0][0]);
    accT[1][0] = MFMA16(bv1, av0, accT[1][0]);
    accT[2][0] = MFMA16(bv2, av0, accT[2][0]);
    accT[3][0] = MFMA16(bv3, av0, accT[3][0]);
    accT[0][1] = MFMA16(bv0, av1, accT[0][1]);
    accT[1][1] = MFMA16(bv1, av1, accT[1][1]);
    accT[2][1] = MFMA16(bv2, av1, accT[2][1]);
    accT[3][1] = MFMA16(bv3, av1, accT[3][1]);
  }
  #pragma unroll
  for (int mi = 0; mi < 2; mi++) {
    float vs = 0.f, vd = 0.f;
    #pragma unroll
    for (int ni = 0; ni < 4; ni++) {
      float4 as4 = *reinterpret_cast<const float4*>(&att_s[head * 64 + ni * 16 + lk * 4]);
      float4 ad4 = *reinterpret_cast<const float4*>(&att_d[head * 64 + ni * 16 + lk * 4]);
      vs += accT[ni][mi][0] * as4.x + accT[ni][mi][1] * as4.y +
            accT[ni][mi][2] * as4.z + accT[ni][mi][3] * as4.w;
      vd += accT[ni][mi][0] * ad4.x + accT[ni][mi][1] * ad4.y +
            accT[ni][mi][2] * ad4.z + accT[ni][mi][3] * ad4.w;
    }
    vs += __shfl_xor(vs, 16); vs += __shfl_xor(vs, 32);
    vd += __shfl_xor(vd, 16); vd += __shfl_xor(vd, 32);
    int row = m0 + mi * 16 + lr;
    if (lk == 0 && row < M) {
      a_src[(size_t)row * 8 + head] = vs;
      a_dst[(size_t)row * 8 + head] = vd;
    }
  }
  unsigned pk[4][2][2];
  #pragma unroll
  for (int ni = 0; ni < 4; ni++)
    #pragma unroll
    for (int mi = 0; mi < 2; mi++) {
      pk[ni][mi][0] = cvtpk(accT[ni][mi][0], accT[ni][mi][1]);
      pk[ni][mi][1] = cvtpk(accT[ni][mi][2], accT[ni][mi][3]);
    }
  f32x4 d3[2] = {};
  #pragma unroll
  for (int kk = 0; kk < 2; kk++) {
    short8 aw2 = *reinterpret_cast<const short8*>(&W2pSa[((size_t)(head * 2 + kk) * 64 + l) * 8]);
    #pragma unroll
    for (int mi = 0; mi < 2; mi++) {
      union { unsigned u[4]; short8 s8; } bf;
      #pragma unroll
      for (int v = 0; v < 4; v++) {
        int src = lr + 16 * ((lk & 1) * 2 + (v >> 1));
        unsigned t0 = __shfl(pk[2 * kk][mi][v & 1], src);
        unsigned t1 = __shfl(pk[2 * kk + 1][mi][v & 1], src);
        bf.u[v] = (lk & 2) ? t1 : t0;
      }
      d3[mi] = MFMA16(aw2, bf.s8, d3[mi]);
    }
  }
  #pragma unroll
  for (int mi = 0; mi < 2; mi++) {
    int row = m0 + mi * 16 + lr;           // d3[mi]: col=lr=xrow, j=lk*4+reg
    if (row < M) {
      uint2 st;
      st.x = cvtpk(d3[mi][0], d3[mi][1]);
      st.y = cvtpk(d3[mi][2], d3[mi][3]);
      *reinterpret_cast<uint2*>(&g1p[(size_t)row * 128 + head * 16 + lk * 4]) = st;
    }
  }
}

// ---------------- FUSED: gat1 softmax-agg over PROJECTED g1p + x@W1p + att3. Unroll 16.
__global__ __launch_bounds__(256)
void agg1_h3_kernel(const int* __restrict__ offs, const int* __restrict__ esrc,
                    const float* __restrict__ a_src1, const float* __restrict__ a_dst1,
                    const bf16* __restrict__ g1p,
                    const float* __restrict__ X,
                    const float* __restrict__ W1pT, const float* __restrict__ b3p,
                    const float* __restrict__ g3_as, const float* __restrict__ g3_ad,
                    bf16* __restrict__ H3b, float* __restrict__ a3s, float* __restrict__ a3d,
                    int N) {
  const int l = threadIdx.x & 63;
  const int n = blockIdx.x * 4 + (threadIdx.x >> 6);
  if (n >= N) return;
  const int g = l >> 3, j0 = l & 7;
  const float adh = a_dst1[n * 8 + g];
  const unsigned* __restrict__ G = reinterpret_cast<const unsigned*>(g1p);  // 64 u32/row
  const int lo = offs[n], hi = offs[n + 1];
  const int gj = g * 8 + j0;
  float agg0 = 0.f, agg1 = 0.f, psum = 0.f;
  int i = lo;
  for (; i + 16 <= hi; i += 16) {        // 16 rows in flight
    int ss[16]; float qq[16]; unsigned ww[16];
    #pragma unroll
    for (int k = 0; k < 16; k++) ss[k] = esrc[i + k];
    #pragma unroll
    for (int k = 0; k < 16; k++) ww[k] = G[(size_t)ss[k] * 64 + gj];
    #pragma unroll
    for (int k = 0; k < 16; k++) qq[k] = a_src1[(size_t)ss[k] * 8 + g];
    #pragma unroll
    for (int k = 0; k < 16; k++) {
      float v = edge_w(qq[k], adh);
      psum += v;
      agg0 = fmaf(v, bflo(ww[k]), agg0);
      agg1 = fmaf(v, bfhi(ww[k]), agg1);
    }
  }
  if (i + 8 <= hi) {
    int ss[8]; float qq[8]; unsigned ww[8];
    #pragma unroll
    for (int k = 0; k < 8; k++) ss[k] = esrc[i + k];
    #pragma unroll
    for (int k = 0; k < 8; k++) ww[k] = G[(size_t)ss[k] * 64 + gj];
    #pragma unroll
    for (int k = 0; k < 8; k++) qq[k] = a_src1[(size_t)ss[k] * 8 + g];
    #pragma unroll
    for (int k = 0; k < 8; k++) {
      float v = edge_w(qq[k], adh);
      psum += v;
      agg0 = fmaf(v, bflo(ww[k]), agg0);
      agg1 = fmaf(v, bfhi(ww[k]), agg1);
    }
    i += 8;
  }
  for (; i < hi; i++) {
    int s = esrc[i];
    float q = a_src1[(size_t)s * 8 + g];
    unsigned w0 = G[(size_t)s * 64 + gj];
    float v = edge_w(q, adh);
    psum += v;
    agg0 = fmaf(v, bflo(w0), agg0); agg1 = fmaf(v, bfhi(w0), agg1);
  }
  const float inv = 1.f / (psum + 1e-16f);
  float v0 = agg0 * inv, v1 = agg1 * inv;
  {
    const float* xr = &X[(size_t)n * 128 + g * 16];
    const float* wr0 = &W1pT[(2 * j0) * 128 + g * 16];
    const float* wr1 = &W1pT[(2 * j0 + 1) * 128 + g * 16];
    #pragma unroll
    for (int c = 0; c < 16; c += 4) {
      float4 xa = *reinterpret_cast<const float4*>(xr + c);
      float4 wa = *reinterpret_cast<const float4*>(wr0 + c);
      float4 wb = *reinterpret_cast<const float4*>(wr1 + c);
      v0 += xa.x * wa.x + xa.y * wa.y + xa.z * wa.z + xa.w * wa.w;
      v1 += xa.x * wb.x + xa.y * wb.y + xa.z * wb.z + xa.w * wb.w;
    }
  }
  v0 += __shfl_xor(v0, 8); v0 += __shfl_xor(v0, 16); v0 += __shfl_xor(v0, 32);
  v1 += __shfl_xor(v1, 8); v1 += __shfl_xor(v1, 16); v1 += __shfl_xor(v1, 32);
  float o0 = v0 + b3p[2 * j0];
  float o1 = v1 + b3p[2 * j0 + 1];
  if (g == 0) reinterpret_cast<unsigned*>(H3b)[(size_t)n * 8 + j0] = cvtpk(o0, o1);
  float vs = o0 * g3_as[2 * j0] + o1 * g3_as[2 * j0 + 1];
  float vd = o0 * g3_ad[2 * j0] + o1 * g3_ad[2 * j0 + 1];
  vs += __shfl_xor(vs, 1); vs += __shfl_xor(vs, 2); vs += __shfl_xor(vs, 4);
  vd += __shfl_xor(vd, 1); vd += __shfl_xor(vd, 2); vd += __shfl_xor(vd, 4);
  if (l == 0) { a3s[n] = vs; a3d[n] = vd; }
}

// ---------------- gat3 aggregation (bf16 H3) -> d_out. Wave/node, 4 groups x 16 ch.
__global__ __launch_bounds__(256)
void agg3_kernel(const int* __restrict__ offs, const int* __restrict__ esrc,
                 const float* __restrict__ a3s, const float* __restrict__ a3d,
                 const bf16* __restrict__ H3b, const float* __restrict__ g3_b,
                 float* __restrict__ out, int N) {
  const int l = threadIdx.x & 63;
  const int n = blockIdx.x * 4 + (threadIdx.x >> 6);
  if (n >= N) return;
  const int g = l >> 4, j = l & 15;
  const float ad = a3d[n];
  const ushort* __restrict__ H = reinterpret_cast<const ushort*>(H3b);
  const int lo = offs[n], hi = offs[n + 1];
  float acc = 0.f, psum = 0.f;
  int i = lo + g;
  for (; i + 12 < hi; i += 16) {
    int s0 = esrc[i], s1 = esrc[i + 4], s2 = esrc[i + 8], s3 = esrc[i + 12];
    float q0 = a3s[s0], q1 = a3s[s1], q2 = a3s[s2], q3 = a3s[s3];
    float h0 = __uint_as_float((unsigned)H[(size_t)s0 * 16 + j] << 16);
    float h1 = __uint_as_float((unsigned)H[(size_t)s1 * 16 + j] << 16);
    float h2 = __uint_as_float((unsigned)H[(size_t)s2 * 16 + j] << 16);
    float h3v = __uint_as_float((unsigned)H[(size_t)s3 * 16 + j] << 16);
    float v0 = edge_w(q0, ad), v1 = edge_w(q1, ad);
    float v2 = edge_w(q2, ad), v3 = edge_w(q3, ad);
    psum += (v0 + v1) + (v2 + v3);
    acc = fmaf(v0, h0, acc); acc = fmaf(v1, h1, acc);
    acc = fmaf(v2, h2, acc); acc = fmaf(v3, h3v, acc);
  }
  for (; i < hi; i += 4) {
    int s = esrc[i];
    float v = edge_w(a3s[s], ad);
    psum += v;
    acc = fmaf(v, __uint_as_float((unsigned)H[(size_t)s * 16 + j] << 16), acc);
  }
  acc += __shfl_xor(acc, 16);  acc += __shfl_xor(acc, 32);
  psum += __shfl_xor(psum, 16); psum += __shfl_xor(psum, 32);
  if (l < 16) out[(size_t)n * 16 + j] = acc / (psum + 1e-16f) + g3_b[j];
}

__global__ void sentinel_kernel(float* out) { out[threadIdx.x] = -1e9f; }

extern "C" void kernel_launch(void* const* d_in, const int* in_sizes, int n_in,
                              void* d_out, int out_size, void* d_ws, size_t ws_size,
                              hipStream_t stream) {
  const float* x      = (const float*)d_in[0];
  const int*   ei     = (const int*)d_in[1];
  const float* g1_W   = (const float*)d_in[2];
  const float* g1_as  = (const float*)d_in[3];
  const float* g1_ad  = (const float*)d_in[4];
  const float* g1_b   = (const float*)d_in[5];
  const float* sk1_W  = (const float*)d_in[6];
  const float* sk1_b  = (const float*)d_in[7];
  const float* sk2_W  = (const float*)d_in[8];
  const float* sk2_b  = (const float*)d_in[9];
  const float* g3_W   = (const float*)d_in[10];
  const float* g3_as  = (const float*)d_in[11];
  const float* g3_ad  = (const float*)d_in[12];
  const float* g3_b   = (const float*)d_in[13];
  float* out = (float*)d_out;

  const int N  = in_sizes[0] / 128;
  const int E  = in_sizes[1] / 2;
  const int EP = E + N;
  const int Mt = (N + 63) / 64;
  const int Np = Mt * 64;
  const int NB = (N + 1023) / 1024;   // scan chunks (<= 256 assumed; 98 here)

  char* w = (char*)d_ws;
  size_t off = 0;
  auto alloc = [&](size_t bytes) -> void* {
    void* p = w + off;
    off = (off + bytes + 255) & ~(size_t)255;
    return p;
  };

  // zero-init block (single memset)
  int* deg    = (int*)alloc((size_t)N * 4);
  int* cursor = (int*)alloc((size_t)N * 4);
  size_t zbytes = off;
  // rest of workspace
  int*   offs   = (int*)alloc((size_t)(N + 1) * 4);
  int*   bsum   = (int*)alloc((size_t)NB * 4);
  int*   esrc   = (int*)alloc((size_t)EP * 4);
  bf16*  xbX    = (bf16*)alloc((size_t)Np * 128 * 2);
  bf16*  WtX    = (bf16*)alloc(512 * 128 * 2);
  bf16*  W2pSa  = (bf16*)alloc(8192 * 2);
  bf16*  g1p    = (bf16*)alloc((size_t)N * 128 * 2);
  float* a_src1 = (float*)alloc((size_t)N * 8 * 4);
  float* a_dst1 = (float*)alloc((size_t)N * 8 * 4);
  bf16*  h3b    = (bf16*)alloc((size_t)N * 16 * 2);
  float* a_src3 = (float*)alloc((size_t)N * 4);
  float* a_dst3 = (float*)alloc((size_t)N * 4);
  float* W1pT   = (float*)alloc(128 * 16 * 4);
  float* W2pT   = (float*)alloc(512 * 16 * 4);
  float* b3p    = (float*)alloc(16 * 4);
  (void)n_in; (void)out_size;

  if (off > ws_size) {  // workspace too small: fail loudly but safely
    sentinel_kernel<<<1, 16, 0, stream>>>(out);
    return;
  }

  hipMemsetAsync(d_ws, 0, zbytes, stream);

  const int eb = (EP + 255) / 256;
  const int nb4 = (N + 3) / 4;
  // mid partition: [0,NB) scan1 | 1024 cast_x | 256 cast_wt | 64 w1p | 256 w2p
  const int b1 = NB + 1024, b2 = b1 + 256, b3 = b2 + 64, b4 = b3 + 256;

  deg_kernel<<<eb, 256, 0, stream>>>(ei, deg, E, EP);

  mid_kernel<<<b4, 256, 0, stream>>>(
      deg, offs, bsum, x, g1_W, sk1_W, sk2_W, g3_W,
      xbX, WtX, W1pT, W2pT, W2pSa, N, Np, NB, b1, b2, b3, b4);

  scan3_setup2_kernel<<<NB + 1, 256, 0, stream>>>(
      offs, bsum, N, NB, sk1_b, sk2_b, g1_b, g3_W, W2pT, b3p);

  gemm_scatter_kernel<<<eb + Mt * 4, 256, 0, stream>>>(
      xbX, WtX, W2pSa, g1_as, g1_ad, g1p, a_src1, a_dst1,
      ei, offs, cursor, esrc, N, Mt, E, EP, eb);

  agg1_h3_kernel<<<nb4, 256, 0, stream>>>(offs, esrc, a_src1, a_dst1, g1p, x,
                                          W1pT, b3p, g3_as, g3_ad,
                                          h3b, a_src3, a_dst3, N);

  agg3_kernel<<<nb4, 256, 0, stream>>>(offs, esrc, a_src3, a_dst3, h3b, g3_b, out, N);
}

// Round 11
// 317.425 us; speedup vs baseline: 2.8050x; 1.0577x over previous
//
#include <hip/hip_runtime.h>
#include <hip/hip_bf16.h>

#define NEG_SLOPE 0.2f
using bf16 = __hip_bfloat16;

typedef __attribute__((ext_vector_type(8))) short short8;   // 8 bf16 (4 VGPRs)
typedef __attribute__((ext_vector_type(4))) float f32x4;
#define MFMA16(a, b, c) __builtin_amdgcn_mfma_f32_16x16x32_bf16(a, b, c, 0, 0, 0)

__device__ __forceinline__ float bflo(unsigned u) { return __uint_as_float(u << 16); }
__device__ __forceinline__ float bfhi(unsigned u) { return __uint_as_float(u & 0xffff0000u); }

__device__ __forceinline__ unsigned cvtpk(float lo, float hi) {
  unsigned r;
  asm volatile("v_cvt_pk_bf16_f32 %0, %1, %2" : "=v"(r) : "v"(lo), "v"(hi));
  return r;
}

__device__ __forceinline__ float edge_w(float q, float adh) {
  float t = q + adh;
  t = (t > 0.f) ? t : NEG_SLOPE * t;
  return __expf(t);
}

// MFMA-fragment packed offset: (tile, kc, lk, r, e) for 16-row tiles, K=128
__device__ __forceinline__ size_t frag_off(int row, int k) {
  return (size_t)(row >> 4) * 2048 + (k >> 5) * 512 + ((k >> 3) & 3) * 128 +
         (row & 15) * 8 + (k & 7);
}

// ---------------- L1 fused: deg+rank | cast_x | cast_wt | w1p | w2p (block-partitioned)
__global__ __launch_bounds__(256)
void setup_kernel(const int* __restrict__ ei, int* __restrict__ deg, int* __restrict__ rank,
                  const float* __restrict__ x, const float* __restrict__ g1_W,
                  const float* __restrict__ sk1_W, const float* __restrict__ sk2_W,
                  const float* __restrict__ g3_W,
                  bf16* __restrict__ xbX, bf16* __restrict__ WtX,
                  float* __restrict__ W1pT, float* __restrict__ W2pT,
                  bf16* __restrict__ W2pSa,
                  int N, int Np, int E, int EP,
                  int bD, int b1, int b2, int b3, int b4) {
  const int b = blockIdx.x;
  const int t = threadIdx.x;
  if (b < bD) {                        // ---- deg histogram + edge rank
    int e = b * 256 + t;
    if (e < EP) {
      int d = (e < E) ? ei[E + e] : (e - E);
      rank[e] = atomicAdd(&deg[d], 1);
    }
  } else if (b < b1) {                 // ---- cast_x -> xbX (packed frag, zero-pad)
    const int total4 = Np * 32;
    const int stride = (b1 - bD) * 256;
    for (int i = (b - bD) * 256 + t; i < total4; i += stride) {
      int row = i >> 5, kq = (i & 31) * 4;
      float4 v = make_float4(0.f, 0.f, 0.f, 0.f);
      if (row < N) v = reinterpret_cast<const float4*>(x)[i];
      union { bf16 bv[4]; ushort4 u; } pk;
      pk.bv[0] = __float2bfloat16(v.x); pk.bv[1] = __float2bfloat16(v.y);
      pk.bv[2] = __float2bfloat16(v.z); pk.bv[3] = __float2bfloat16(v.w);
      *reinterpret_cast<ushort4*>(&xbX[frag_off(row, kq)]) = pk.u;
    }
  } else if (b < b2) {                 // ---- cast_wt -> WtX (packed frag)
    int i = (b - b1) * 256 + t;        // 65536 exactly
    int k = i >> 9, c = i & 511;
    WtX[frag_off(c, k)] = __float2bfloat16(g1_W[k * 512 + c]);
  } else if (b < b3) {                 // ---- w1p: 2048 outputs x 8 thr
    int i = (b - b2) * 256 + t;        // < 16384
    int o = i >> 3, seg = i & 7;
    int j = o >> 7, k = o & 127;
    float acc = 0.f;
    for (int m = seg * 64; m < seg * 64 + 64; m++)
      acc += sk1_W[k * 512 + m] * g3_W[m * 16 + j];
    acc += __shfl_xor(acc, 1); acc += __shfl_xor(acc, 2); acc += __shfl_xor(acc, 4);
    if (seg == 0) W1pT[o] = acc;
  } else if (b < b4) {                 // ---- w2p: 8192 outputs x 8 thr (+W2pSa frags)
    int i = (b - b3) * 256 + t;        // < 65536
    int o = i >> 3, seg = i & 7;
    int j = o >> 9, c = o & 511;
    float acc = 0.f;
    for (int m = seg * 64; m < seg * 64 + 64; m++)
      acc += sk2_W[c * 512 + m] * g3_W[(512 + m) * 16 + j];
    acc += __shfl_xor(acc, 1); acc += __shfl_xor(acc, 2); acc += __shfl_xor(acc, 4);
    if (seg == 0) {
      W2pT[o] = acc;
      int h = c >> 6, cc = c & 63, kk = cc >> 5, lk = (cc >> 3) & 3, e = cc & 7;
      W2pSa[((size_t)(h * 2 + kk) * 64 + (j + 16 * lk)) * 8 + e] = __float2bfloat16(acc);
    }
  }
}

// ---------------- L2: scan1 (per-1024-chunk excl scan) | setup2 (b3p)
__global__ __launch_bounds__(256)
void scan1_setup2_kernel(const int* __restrict__ deg, int* __restrict__ offs,
                         int* __restrict__ bsum, int n, int NB,
                         const float* __restrict__ sk1_b, const float* __restrict__ sk2_b,
                         const float* __restrict__ g1_b, const float* __restrict__ g3_W,
                         const float* __restrict__ W2pT, float* __restrict__ b3p) {
  const int b = blockIdx.x, t = threadIdx.x;
  if (b == NB) {                      // setup2
    __shared__ float red[16][16];
    int j = t & 15, seg = t >> 4;
    float acc = 0.f;
    for (int m = seg * 32; m < seg * 32 + 32; m++)
      acc += sk1_b[m] * g3_W[m * 16 + j] + sk2_b[m] * g3_W[(512 + m) * 16 + j];
    for (int c = seg * 32; c < seg * 32 + 32; c++)
      acc += g1_b[c] * W2pT[j * 512 + c];
    red[seg][j] = acc;
    __syncthreads();
    if (t < 16) {
      float s = 0.f;
      for (int k = 0; k < 16; k++) s += red[k][t];
      b3p[t] = s;
    }
    return;
  }
  __shared__ int ts[256];
  const int base = b * 1024 + t * 4;
  int4 v = make_int4(0, 0, 0, 0);
  if (base + 3 < n) v = *reinterpret_cast<const int4*>(&deg[base]);
  else {
    if (base + 0 < n) v.x = deg[base + 0];
    if (base + 1 < n) v.y = deg[base + 1];
    if (base + 2 < n) v.z = deg[base + 2];
  }
  ts[t] = v.x + v.y + v.z + v.w;
  __syncthreads();
  for (int st = 1; st < 256; st <<= 1) {
    int u = (t >= st) ? ts[t - st] : 0;
    __syncthreads();
    ts[t] += u;
    __syncthreads();
  }
  int excl = (t == 0) ? 0 : ts[t - 1];
  int4 o;
  o.x = excl; o.y = o.x + v.x; o.z = o.y + v.y; o.w = o.z + v.z;
  if (base + 3 < n) *reinterpret_cast<int4*>(&offs[base]) = o;
  else {
    if (base + 0 < n) offs[base + 0] = o.x;
    if (base + 1 < n) offs[base + 1] = o.y;
    if (base + 2 < n) offs[base + 2] = o.z;
  }
  if (t == 255) bsum[b] = ts[255];
}

// ---------------- L3: scan3 — each block self-computes prefix of bsum[0..b) and adds
__global__ __launch_bounds__(256)
void scan3_kernel(int* __restrict__ offs, const int* __restrict__ bsum, int n, int NB) {
  __shared__ int wred[4];
  const int b = blockIdx.x, t = threadIdx.x;
  int part = (t < b) ? bsum[t] : 0;            // NB <= 256 assumed
  #pragma unroll
  for (int m = 1; m < 64; m <<= 1) part += __shfl_xor(part, m);
  if ((t & 63) == 0) wred[t >> 6] = part;
  __syncthreads();
  const int add = wred[0] + wred[1] + wred[2] + wred[3];
  if (b == NB - 1 && t == 0) offs[n] = add + bsum[b];
  if (add == 0) return;
  const int base = b * 1024 + t * 4;
  if (base + 3 < n) {
    int4 o = *reinterpret_cast<const int4*>(&offs[base]);
    o.x += add; o.y += add; o.z += add; o.w += add;
    *reinterpret_cast<int4*>(&offs[base]) = o;
  } else {
    if (base + 0 < n) offs[base + 0] += add;
    if (base + 1 < n) offs[base + 1] += add;
    if (base + 2 < n) offs[base + 2] += add;
  }
}

// ---------------- L4: CSR scatter (atomic-free, blocks first)  ||  MFMA GEMM
__global__ __launch_bounds__(256)
void gemm_scatter_kernel(const bf16* __restrict__ xbX, const bf16* __restrict__ WtX,
                         const bf16* __restrict__ W2pSa,
                         const float* __restrict__ att_s, const float* __restrict__ att_d,
                         bf16* __restrict__ g1p, float* __restrict__ a_src,
                         float* __restrict__ a_dst,
                         const int* __restrict__ ei, const int* __restrict__ offs,
                         const int* __restrict__ rank, int* __restrict__ esrc,
                         int M, int Mt, int E, int EP, int eb) {
  if (blockIdx.x < eb) {              // ---- scatter (no atomics: rank precomputed)
    int e = blockIdx.x * 256 + threadIdx.x;
    if (e < EP) {
      int s = (e < E) ? ei[e] : (e - E);
      int d = (e < E) ? ei[E + e] : (e - E);
      esrc[offs[d] + rank[e]] = s;
    }
    return;
  }
  // ---- gemm part
  const int gb = blockIdx.x - eb;
  const int bx = gb % Mt;
  const int by = gb / Mt;
  const int t = threadIdx.x;
  const int w = t >> 6, l = t & 63;
  const int wm = w & 1, wn = w >> 1;
  const int m0 = bx * 64 + wm * 32;
  const int n0 = by * 128 + wn * 64;
  const int head = n0 >> 6;
  const int lr = l & 15, lk = l >> 4;
  const bf16* aBase = xbX + (size_t)(m0 >> 4) * 2048 + l * 8;
  const bf16* bBase = WtX + (size_t)(n0 >> 4) * 2048 + l * 8;
  f32x4 accT[4][2] = {};   // accT[ni][mi]: lane holds h1[xrow=mi*16+lr, wcol=ni*16+lk*4+r]
  #pragma unroll
  for (int kc = 0; kc < 4; kc++) {
    short8 av0 = *reinterpret_cast<const short8*>(aBase + kc * 512);
    short8 av1 = *reinterpret_cast<const short8*>(aBase + 2048 + kc * 512);
    short8 bv0 = *reinterpret_cast<const short8*>(bBase + 0 * 2048 + kc * 512);
    short8 bv1 = *reinterpret_cast<const short8*>(bBase + 1 * 2048 + kc * 512);
    short8 bv2 = *reinterpret_cast<const short8*>(bBase + 2 * 2048 + kc * 512);
    short8 bv3 = *reinterpret_cast<const short8*>(bBase + 3 * 2048 + kc * 512);
    accT[0][0] = MFMA16(bv0, av0, accT[0][0]);
    accT[1][0] = MFMA16(bv1, av0, accT[1][0]);
    accT[2][0] = MFMA16(bv2, av0, accT[2][0]);
    accT[3][0] = MFMA16(bv3, av0, accT[3][0]);
    accT[0][1] = MFMA16(bv0, av1, accT[0][1]);
    accT[1][1] = MFMA16(bv1, av1, accT[1][1]);
    accT[2][1] = MFMA16(bv2, av1, accT[2][1]);
    accT[3][1] = MFMA16(bv3, av1, accT[3][1]);
  }
  #pragma unroll
  for (int mi = 0; mi < 2; mi++) {
    float vs = 0.f, vd = 0.f;
    #pragma unroll
    for (int ni = 0; ni < 4; ni++) {
      float4 as4 = *reinterpret_cast<const float4*>(&att_s[head * 64 + ni * 16 + lk * 4]);
      float4 ad4 = *reinterpret_cast<const float4*>(&att_d[head * 64 + ni * 16 + lk * 4]);
      vs += accT[ni][mi][0] * as4.x + accT[ni][mi][1] * as4.y +
            accT[ni][mi][2] * as4.z + accT[ni][mi][3] * as4.w;
      vd += accT[ni][mi][0] * ad4.x + accT[ni][mi][1] * ad4.y +
            accT[ni][mi][2] * ad4.z + accT[ni][mi][3] * ad4.w;
    }
    vs += __shfl_xor(vs, 16); vs += __shfl_xor(vs, 32);
    vd += __shfl_xor(vd, 16); vd += __shfl_xor(vd, 32);
    int row = m0 + mi * 16 + lr;
    if (lk == 0 && row < M) {
      a_src[(size_t)row * 8 + head] = vs;
      a_dst[(size_t)row * 8 + head] = vd;
    }
  }
  unsigned pk[4][2][2];
  #pragma unroll
  for (int ni = 0; ni < 4; ni++)
    #pragma unroll
    for (int mi = 0; mi < 2; mi++) {
      pk[ni][mi][0] = cvtpk(accT[ni][mi][0], accT[ni][mi][1]);
      pk[ni][mi][1] = cvtpk(accT[ni][mi][2], accT[ni][mi][3]);
    }
  f32x4 d3[2] = {};
  #pragma unroll
  for (int kk = 0; kk < 2; kk++) {
    short8 aw2 = *reinterpret_cast<const short8*>(&W2pSa[((size_t)(head * 2 + kk) * 64 + l) * 8]);
    #pragma unroll
    for (int mi = 0; mi < 2; mi++) {
      union { unsigned u[4]; short8 s8; } bf;
      #pragma unroll
      for (int v = 0; v < 4; v++) {
        int src = lr + 16 * ((lk & 1) * 2 + (v >> 1));
        unsigned t0 = __shfl(pk[2 * kk][mi][v & 1], src);
        unsigned t1 = __shfl(pk[2 * kk + 1][mi][v & 1], src);
        bf.u[v] = (lk & 2) ? t1 : t0;
      }
      d3[mi] = MFMA16(aw2, bf.s8, d3[mi]);
    }
  }
  #pragma unroll
  for (int mi = 0; mi < 2; mi++) {
    int row = m0 + mi * 16 + lr;           // d3[mi]: col=lr=xrow, j=lk*4+reg
    if (row < M) {
      uint2 st;
      st.x = cvtpk(d3[mi][0], d3[mi][1]);
      st.y = cvtpk(d3[mi][2], d3[mi][3]);
      *reinterpret_cast<uint2*>(&g1p[(size_t)row * 128 + head * 16 + lk * 4]) = st;
    }
  }
}

// ---------------- L5: gat1 softmax-agg over PROJECTED g1p + x@W1p + att3. Unroll 16.
__global__ __launch_bounds__(256)
void agg1_h3_kernel(const int* __restrict__ offs, const int* __restrict__ esrc,
                    const float* __restrict__ a_src1, const float* __restrict__ a_dst1,
                    const bf16* __restrict__ g1p,
                    const float* __restrict__ X,
                    const float* __restrict__ W1pT, const float* __restrict__ b3p,
                    const float* __restrict__ g3_as, const float* __restrict__ g3_ad,
                    bf16* __restrict__ H3b, float* __restrict__ a3s, float* __restrict__ a3d,
                    int N) {
  const int l = threadIdx.x & 63;
  const int n = blockIdx.x * 4 + (threadIdx.x >> 6);
  if (n >= N) return;
  const int g = l >> 3, j0 = l & 7;
  const float adh = a_dst1[n * 8 + g];
  const unsigned* __restrict__ G = reinterpret_cast<const unsigned*>(g1p);  // 64 u32/row
  const int lo = offs[n], hi = offs[n + 1];
  const int gj = g * 8 + j0;
  float agg0 = 0.f, agg1 = 0.f, psum = 0.f;
  int i = lo;
  for (; i + 16 <= hi; i += 16) {        // 16 rows in flight
    int ss[16]; float qq[16]; unsigned ww[16];
    #pragma unroll
    for (int k = 0; k < 16; k++) ss[k] = esrc[i + k];
    #pragma unroll
    for (int k = 0; k < 16; k++) ww[k] = G[(size_t)ss[k] * 64 + gj];
    #pragma unroll
    for (int k = 0; k < 16; k++) qq[k] = a_src1[(size_t)ss[k] * 8 + g];
    #pragma unroll
    for (int k = 0; k < 16; k++) {
      float v = edge_w(qq[k], adh);
      psum += v;
      agg0 = fmaf(v, bflo(ww[k]), agg0);
      agg1 = fmaf(v, bfhi(ww[k]), agg1);
    }
  }
  if (i + 8 <= hi) {
    int ss[8]; float qq[8]; unsigned ww[8];
    #pragma unroll
    for (int k = 0; k < 8; k++) ss[k] = esrc[i + k];
    #pragma unroll
    for (int k = 0; k < 8; k++) ww[k] = G[(size_t)ss[k] * 64 + gj];
    #pragma unroll
    for (int k = 0; k < 8; k++) qq[k] = a_src1[(size_t)ss[k] * 8 + g];
    #pragma unroll
    for (int k = 0; k < 8; k++) {
      float v = edge_w(qq[k], adh);
      psum += v;
      agg0 = fmaf(v, bflo(ww[k]), agg0);
      agg1 = fmaf(v, bfhi(ww[k]), agg1);
    }
    i += 8;
  }
  for (; i < hi; i++) {
    int s = esrc[i];
    float q = a_src1[(size_t)s * 8 + g];
    unsigned w0 = G[(size_t)s * 64 + gj];
    float v = edge_w(q, adh);
    psum += v;
    agg0 = fmaf(v, bflo(w0), agg0); agg1 = fmaf(v, bfhi(w0), agg1);
  }
  const float inv = 1.f / (psum + 1e-16f);
  float v0 = agg0 * inv, v1 = agg1 * inv;
  {
    const float* xr = &X[(size_t)n * 128 + g * 16];
    const float* wr0 = &W1pT[(2 * j0) * 128 + g * 16];
    const float* wr1 = &W1pT[(2 * j0 + 1) * 128 + g * 16];
    #pragma unroll
    for (int c = 0; c < 16; c += 4) {
      float4 xa = *reinterpret_cast<const float4*>(xr + c);
      float4 wa = *reinterpret_cast<const float4*>(wr0 + c);
      float4 wb = *reinterpret_cast<const float4*>(wr1 + c);
      v0 += xa.x * wa.x + xa.y * wa.y + xa.z * wa.z + xa.w * wa.w;
      v1 += xa.x * wb.x + xa.y * wb.y + xa.z * wb.z + xa.w * wb.w;
    }
  }
  v0 += __shfl_xor(v0, 8); v0 += __shfl_xor(v0, 16); v0 += __shfl_xor(v0, 32);
  v1 += __shfl_xor(v1, 8); v1 += __shfl_xor(v1, 16); v1 += __shfl_xor(v1, 32);
  float o0 = v0 + b3p[2 * j0];
  float o1 = v1 + b3p[2 * j0 + 1];
  if (g == 0) reinterpret_cast<unsigned*>(H3b)[(size_t)n * 8 + j0] = cvtpk(o0, o1);
  float vs = o0 * g3_as[2 * j0] + o1 * g3_as[2 * j0 + 1];
  float vd = o0 * g3_ad[2 * j0] + o1 * g3_ad[2 * j0 + 1];
  vs += __shfl_xor(vs, 1); vs += __shfl_xor(vs, 2); vs += __shfl_xor(vs, 4);
  vd += __shfl_xor(vd, 1); vd += __shfl_xor(vd, 2); vd += __shfl_xor(vd, 4);
  if (l == 0) { a3s[n] = vs; a3d[n] = vd; }
}

// ---------------- L6: gat3 aggregation (bf16 H3) -> d_out. Wave/node, 4 groups x 16 ch.
__global__ __launch_bounds__(256)
void agg3_kernel(const int* __restrict__ offs, const int* __restrict__ esrc,
                 const float* __restrict__ a3s, const float* __restrict__ a3d,
                 const bf16* __restrict__ H3b, const float* __restrict__ g3_b,
                 float* __restrict__ out, int N) {
  const int l = threadIdx.x & 63;
  const int n = blockIdx.x * 4 + (threadIdx.x >> 6);
  if (n >= N) return;
  const int g = l >> 4, j = l & 15;
  const float ad = a3d[n];
  const ushort* __restrict__ H = reinterpret_cast<const ushort*>(H3b);
  const int lo = offs[n], hi = offs[n + 1];
  float acc = 0.f, psum = 0.f;
  int i = lo + g;
  for (; i + 12 < hi; i += 16) {
    int s0 = esrc[i], s1 = esrc[i + 4], s2 = esrc[i + 8], s3 = esrc[i + 12];
    float q0 = a3s[s0], q1 = a3s[s1], q2 = a3s[s2], q3 = a3s[s3];
    float h0 = __uint_as_float((unsigned)H[(size_t)s0 * 16 + j] << 16);
    float h1 = __uint_as_float((unsigned)H[(size_t)s1 * 16 + j] << 16);
    float h2 = __uint_as_float((unsigned)H[(size_t)s2 * 16 + j] << 16);
    float h3v = __uint_as_float((unsigned)H[(size_t)s3 * 16 + j] << 16);
    float v0 = edge_w(q0, ad), v1 = edge_w(q1, ad);
    float v2 = edge_w(q2, ad), v3 = edge_w(q3, ad);
    psum += (v0 + v1) + (v2 + v3);
    acc = fmaf(v0, h0, acc); acc = fmaf(v1, h1, acc);
    acc = fmaf(v2, h2, acc); acc = fmaf(v3, h3v, acc);
  }
  for (; i < hi; i += 4) {
    int s = esrc[i];
    float v = edge_w(a3s[s], ad);
    psum += v;
    acc = fmaf(v, __uint_as_float((unsigned)H[(size_t)s * 16 + j] << 16), acc);
  }
  acc += __shfl_xor(acc, 16);  acc += __shfl_xor(acc, 32);
  psum += __shfl_xor(psum, 16); psum += __shfl_xor(psum, 32);
  if (l < 16) out[(size_t)n * 16 + j] = acc / (psum + 1e-16f) + g3_b[j];
}

__global__ void sentinel_kernel(float* out) { out[threadIdx.x] = -1e9f; }

extern "C" void kernel_launch(void* const* d_in, const int* in_sizes, int n_in,
                              void* d_out, int out_size, void* d_ws, size_t ws_size,
                              hipStream_t stream) {
  const float* x      = (const float*)d_in[0];
  const int*   ei     = (const int*)d_in[1];
  const float* g1_W   = (const float*)d_in[2];
  const float* g1_as  = (const float*)d_in[3];
  const float* g1_ad  = (const float*)d_in[4];
  const float* g1_b   = (const float*)d_in[5];
  const float* sk1_W  = (const float*)d_in[6];
  const float* sk1_b  = (const float*)d_in[7];
  const float* sk2_W  = (const float*)d_in[8];
  const float* sk2_b  = (const float*)d_in[9];
  const float* g3_W   = (const float*)d_in[10];
  const float* g3_as  = (const float*)d_in[11];
  const float* g3_ad  = (const float*)d_in[12];
  const float* g3_b   = (const float*)d_in[13];
  float* out = (float*)d_out;

  const int N  = in_sizes[0] / 128;
  const int E  = in_sizes[1] / 2;
  const int EP = E + N;
  const int Mt = (N + 63) / 64;
  const int Np = Mt * 64;
  const int NB = (N + 1023) / 1024;   // scan chunks (<= 256 assumed; 98 here)

  char* w = (char*)d_ws;
  size_t off = 0;
  auto alloc = [&](size_t bytes) -> void* {
    void* p = w + off;
    off = (off + bytes + 255) & ~(size_t)255;
    return p;
  };

  // zero-init block (single memset)
  int* deg    = (int*)alloc((size_t)N * 4);
  size_t zbytes = off;
  // rest of workspace
  int*   offs   = (int*)alloc((size_t)(N + 1) * 4);
  int*   bsum   = (int*)alloc((size_t)NB * 4);
  int*   rank   = (int*)alloc((size_t)EP * 4);
  int*   esrc   = (int*)alloc((size_t)EP * 4);
  bf16*  xbX    = (bf16*)alloc((size_t)Np * 128 * 2);
  bf16*  WtX    = (bf16*)alloc(512 * 128 * 2);
  bf16*  W2pSa  = (bf16*)alloc(8192 * 2);
  bf16*  g1p    = (bf16*)alloc((size_t)N * 128 * 2);
  float* a_src1 = (float*)alloc((size_t)N * 8 * 4);
  float* a_dst1 = (float*)alloc((size_t)N * 8 * 4);
  bf16*  h3b    = (bf16*)alloc((size_t)N * 16 * 2);
  float* a_src3 = (float*)alloc((size_t)N * 4);
  float* a_dst3 = (float*)alloc((size_t)N * 4);
  float* W1pT   = (float*)alloc(128 * 16 * 4);
  float* W2pT   = (float*)alloc(512 * 16 * 4);
  float* b3p    = (float*)alloc(16 * 4);
  (void)n_in; (void)out_size;

  if (off > ws_size) {  // workspace too small: fail loudly but safely
    sentinel_kernel<<<1, 16, 0, stream>>>(out);
    return;
  }

  hipMemsetAsync(d_ws, 0, zbytes, stream);

  const int eb = (EP + 255) / 256;
  const int nb4 = (N + 3) / 4;
  // L1 partition: [0,eb) deg+rank | 1024 cast_x | 256 cast_wt | 64 w1p | 256 w2p
  const int bD = eb, b1 = bD + 1024, b2 = b1 + 256, b3 = b2 + 64, b4 = b3 + 256;

  setup_kernel<<<b4, 256, 0, stream>>>(
      ei, deg, rank, x, g1_W, sk1_W, sk2_W, g3_W,
      xbX, WtX, W1pT, W2pT, W2pSa, N, Np, E, EP, bD, b1, b2, b3, b4);

  scan1_setup2_kernel<<<NB + 1, 256, 0, stream>>>(
      deg, offs, bsum, N, NB, sk1_b, sk2_b, g1_b, g3_W, W2pT, b3p);

  scan3_kernel<<<NB, 256, 0, stream>>>(offs, bsum, N, NB);

  gemm_scatter_kernel<<<eb + Mt * 4, 256, 0, stream>>>(
      xbX, WtX, W2pSa, g1_as, g1_ad, g1p, a_src1, a_dst1,
      ei, offs, rank, esrc, N, Mt, E, EP, eb);

  agg1_h3_kernel<<<nb4, 256, 0, stream>>>(offs, esrc, a_src1, a_dst1, g1p, x,
                                          W1pT, b3p, g3_as, g3_ad,
                                          h3b, a_src3, a_dst3, N);

  agg3_kernel<<<nb4, 256, 0, stream>>>(offs, esrc, a_src3, a_dst3, h3b, g3_b, out, N);
}